// Round 1
// baseline (35363.544 us; speedup 1.0000x reference)
//
#include <hip/hip_runtime.h>

// LSTM autoencoder, MI355X. Round 3: single persistent cooperative kernel.
// All 1024 sequential steps run inside one launch (256 blocks x 512 thr,
// 1 block/CU); steps separated by a device-scope grid barrier (atomic gen
// flip + __threadfence for cross-XCD h visibility). Weights are
// register-resident (64+16 VGPR of half8 fragments, loop-invariant), cell
// state c is one register/thread, biases hoisted. Eliminates ~1024 launch
// overheads + per-step 147KB/block L2 weight re-stream + cbuf global traffic.

#define BB 128
#define SS 512
#define DD 128
#define HH 1024
#define G4 4096
#define KENC 1152
#define NBLK 256

typedef _Float16 half8 __attribute__((ext_vector_type(8)));
typedef float floatx4 __attribute__((ext_vector_type(4)));

__device__ __forceinline__ float sigf(float x) { return 1.0f / (1.0f + __expf(-x)); }
__device__ __forceinline__ float tanhfast(float x) { return 1.0f - 2.0f / (1.0f + __expf(2.0f * x)); }

#define MFMA16(a, b, c) __builtin_amdgcn_mfma_f32_16x16x32_f16((a), (b), (c), 0, 0, 0)

// ---- prep kernels -----------------------------------------------------------

__global__ void k_prep_encw(const float* __restrict__ eWih, const float* __restrict__ eWhh,
                            _Float16* __restrict__ encW) {
  int r = blockIdx.x;  // 0..4095
  for (int k = threadIdx.x; k < KENC; k += blockDim.x) {
    float v = (k < DD) ? eWih[(size_t)r * DD + k] : eWhh[(size_t)r * HH + (k - DD)];
    encW[(size_t)r * KENC + k] = (_Float16)v;
  }
}

__global__ void k_prep_simple(const float* __restrict__ dWih, const float* __restrict__ dWhh,
                              const float* __restrict__ oW,
                              const float* __restrict__ eBih, const float* __restrict__ eBhh,
                              const float* __restrict__ dBih, const float* __restrict__ dBhh,
                              const float* __restrict__ oB,
                              _Float16* __restrict__ decW1, _Float16* __restrict__ outW16,
                              float* __restrict__ encB, float* __restrict__ decB1,
                              float* __restrict__ decB2,
                              _Float16* __restrict__ hA, float* __restrict__ lossAcc,
                              unsigned* __restrict__ bar) {
  int tid = blockIdx.x * blockDim.x + threadIdx.x;
  int nt = gridDim.x * blockDim.x;
  for (size_t i = tid; i < (size_t)G4 * HH; i += nt)
    decW1[i] = (_Float16)(dWih[i] + dWhh[i]);   // dec step1: inp==h_n -> Wih+Whh
  for (size_t i = tid; i < (size_t)DD * HH; i += nt)
    outW16[i] = (_Float16)oW[i];
  for (size_t i = tid; i < (size_t)BB * HH; i += nt)
    hA[i] = (_Float16)0.0f;
  if (tid == 0) { lossAcc[0] = 0.0f; bar[0] = 0u; bar[1] = 0u; }
  if (tid < G4) {
    encB[tid] = eBih[tid] + eBhh[tid];
    float b1 = dBih[tid] + dBhh[tid];
    decB1[tid] = b1;
    float acc = b1;  // b2 = b1 + dec_Wih[:,:D] @ out_b
    for (int j = 0; j < DD; ++j) acc += dWih[(size_t)tid * HH + j] * oB[j];
    decB2[tid] = acc;
  }
}

// W2 = dec_Whh + dec_Wih[:,:D] @ out_W   (4096 x 1024)
__global__ void k_prep_decw2(const float* __restrict__ dWih, const float* __restrict__ dWhh,
                             const float* __restrict__ oW, _Float16* __restrict__ decW2) {
  int r = blockIdx.x >> 2;                       // 0..4095
  int c = ((blockIdx.x & 3) << 8) + threadIdx.x; // 0..1023
  float acc = dWhh[(size_t)r * HH + c];
  for (int j = 0; j < DD; ++j) acc += dWih[(size_t)r * HH + j] * oW[(size_t)j * HH + c];
  decW2[(size_t)r * HH + c] = (_Float16)acc;
}

// ---- grid barrier -----------------------------------------------------------
// Sense via monotonically increasing generation; each block tracks the target
// locally (no pre-read race). __threadfence (agent scope) = wbl2+inv on gfx950:
// release makes this XCD's dirty h lines visible in L3, acquire invalidates
// stale lines before the next step's h reads.
__device__ __forceinline__ void grid_barrier(unsigned* bar, unsigned target) {
  __syncthreads();  // drains each thread's vmem stores into L2 before fence
  if (threadIdx.x == 0) {
    __threadfence();
    unsigned old = __hip_atomic_fetch_add(&bar[0], 1u, __ATOMIC_ACQ_REL, __HIP_MEMORY_SCOPE_AGENT);
    if (old == NBLK - 1) {
      __hip_atomic_store(&bar[0], 0u, __ATOMIC_RELAXED, __HIP_MEMORY_SCOPE_AGENT);
      __hip_atomic_store(&bar[1], target, __ATOMIC_RELEASE, __HIP_MEMORY_SCOPE_AGENT);
    } else {
      while (__hip_atomic_load(&bar[1], __ATOMIC_ACQUIRE, __HIP_MEMORY_SCOPE_AGENT) < target)
        __builtin_amdgcn_s_sleep(1);
    }
    __threadfence();
  }
  __syncthreads();
}

// ---- persistent sequence kernel --------------------------------------------
// Grid 256 = (mtb 0..3)<<6 | (ut 0..63); 512 threads = 8 waves (K-split).
// MFMA 16x16x32_f16: A[m=lane&15][k=(lane>>4)*8+j], B[n=lane&15][k=...],
// C/D: row=(lane>>4)*4+reg, col=lane&15.

__global__ __launch_bounds__(512, 2) void k_seq(
    const float* __restrict__ x, const _Float16* __restrict__ encW,
    const float* __restrict__ encB,
    const _Float16* __restrict__ decW1, const _Float16* __restrict__ decW2,
    const float* __restrict__ decB1, const float* __restrict__ decB2,
    const _Float16* __restrict__ outW, const float* __restrict__ oB,
    _Float16* __restrict__ hA, _Float16* __restrict__ hB,
    float* __restrict__ encOut, float* __restrict__ recon,
    float* __restrict__ lossAcc, float* __restrict__ lossOut,
    unsigned* __restrict__ bar) {
  __shared__ float pl[4][4][2][16][16];   // [slot][gate][mtile][row][col] 32 KB
  __shared__ float red[4][2][16][16];     // 8 KB
  __shared__ float pY[4][2][16][16];      // 8 KB
  __shared__ float redY[2][16][16];       // 2 KB

  const int tid = threadIdx.x;
  const int lane = tid & 63, w = tid >> 6;
  const int n = lane & 15, q = lane >> 4;
  const int ut = (int)blockIdx.x & 63, mtb = (int)blockIdx.x >> 6;
  const int m0 = mtb << 5, u0 = ut << 4;
  const int kh0 = w << 7;   // this wave's 128-wide K slice of the h part

  // step-invariant cell-update mapping: thread tid -> (m_l = tid>>4, u_l = tid&15)
  const int m_l = tid >> 4, u_l = tid & 15;
  const int mtc = m_l >> 4, rowc = m_l & 15;
  const int cm = m0 + m_l, cu = u0 + u_l;
  const size_t hidx = (size_t)cm * HH + cu;

  unsigned barIdx = 0;
  float creg = 0.0f;        // cell state c[cm][cu] lives here for all 1024 steps

  // -------- encoder weights -> registers (loop-invariant) --------
  half8 bw[4][4];           // [gate][kk] : 64 VGPR
  half8 xw[4];              // x-part fragments (waves 0..3 only) : 16 VGPR
  {
    const _Float16* base = encW + (size_t)(u0 + n) * KENC + (size_t)(DD + kh0 + q * 8);
#pragma unroll
    for (int g = 0; g < 4; ++g)
#pragma unroll
      for (int kk = 0; kk < 4; ++kk)
        bw[g][kk] = *(const half8*)(base + (size_t)g * ((size_t)HH * KENC) + kk * 32);
    if (w < 4) {
      const _Float16* xb = encW + (size_t)(u0 + n) * KENC + (size_t)((w << 5) + q * 8);
#pragma unroll
      for (int g = 0; g < 4; ++g)
        xw[g] = *(const half8*)(xb + (size_t)g * ((size_t)HH * KENC));
    }
  }
  float b0 = encB[cu], b1 = encB[HH + cu], b2 = encB[2 * HH + cu], b3 = encB[3 * HH + cu];

  // step-invariant pointers
  const _Float16* hrowA = hA + (size_t)(m0 + n) * HH + kh0 + q * 8;
  const _Float16* hrowB = hB + (size_t)(m0 + n) * HH + kh0 + q * 8;
  const float* xr0base = x + (size_t)(m0 + n) * ((size_t)SS * DD) + (size_t)((w << 5) + q * 8);
  const float* xr1base = xr0base + (size_t)16 * ((size_t)SS * DD);
  float* encPtr = encOut + (size_t)cm * ((size_t)SS * HH) + cu;

  // ================= encoder =================
  for (int t = 0; t < SS; ++t) {
    const _Float16* h0 = (t & 1) ? hrowB : hrowA;
    _Float16* hout = (t & 1) ? hA : hB;
    const _Float16* h1 = h0 + (size_t)16 * HH;

    floatx4 acc[4][2];
#pragma unroll
    for (int g = 0; g < 4; ++g) {
      acc[g][0] = (floatx4){0, 0, 0, 0};
      acc[g][1] = (floatx4){0, 0, 0, 0};
    }
#pragma unroll
    for (int kk = 0; kk < 4; ++kk) {
      half8 a0 = *(const half8*)(h0 + kk * 32);
      half8 a1 = *(const half8*)(h1 + kk * 32);
      acc[0][0] = MFMA16(a0, bw[0][kk], acc[0][0]); acc[0][1] = MFMA16(a1, bw[0][kk], acc[0][1]);
      acc[1][0] = MFMA16(a0, bw[1][kk], acc[1][0]); acc[1][1] = MFMA16(a1, bw[1][kk], acc[1][1]);
      acc[2][0] = MFMA16(a0, bw[2][kk], acc[2][0]); acc[2][1] = MFMA16(a1, bw[2][kk], acc[2][1]);
      acc[3][0] = MFMA16(a0, bw[3][kk], acc[3][0]); acc[3][1] = MFMA16(a1, bw[3][kk], acc[3][1]);
    }
    if (w < 4) {  // waves 0..3 take the x part (K=128, 32 each)
      const float* xr0 = xr0base + (size_t)t * DD;
      const float* xr1 = xr1base + (size_t)t * DD;
      floatx4 p0 = *(const floatx4*)xr0;
      floatx4 p1 = *(const floatx4*)(xr0 + 4);
      floatx4 p2 = *(const floatx4*)xr1;
      floatx4 p3 = *(const floatx4*)(xr1 + 4);
      half8 a0, a1;
#pragma unroll
      for (int j = 0; j < 4; ++j) {
        a0[j] = (_Float16)p0[j]; a0[j + 4] = (_Float16)p1[j];
        a1[j] = (_Float16)p2[j]; a1[j + 4] = (_Float16)p3[j];
      }
      acc[0][0] = MFMA16(a0, xw[0], acc[0][0]); acc[0][1] = MFMA16(a1, xw[0], acc[0][1]);
      acc[1][0] = MFMA16(a0, xw[1], acc[1][0]); acc[1][1] = MFMA16(a1, xw[1], acc[1][1]);
      acc[2][0] = MFMA16(a0, xw[2], acc[2][0]); acc[2][1] = MFMA16(a1, xw[2], acc[2][1]);
      acc[3][0] = MFMA16(a0, xw[3], acc[3][0]); acc[3][1] = MFMA16(a1, xw[3], acc[3][1]);
    }

    // 2-level reduction tree over the 8 K-slices
    if (w >= 4) {
#pragma unroll
      for (int g = 0; g < 4; ++g)
#pragma unroll
        for (int mt = 0; mt < 2; ++mt)
#pragma unroll
          for (int r = 0; r < 4; ++r)
            pl[w - 4][g][mt][q * 4 + r][n] = acc[g][mt][r];
    }
    __syncthreads();
    if (w < 4) {
#pragma unroll
      for (int g = 0; g < 4; ++g)
#pragma unroll
        for (int mt = 0; mt < 2; ++mt)
#pragma unroll
          for (int r = 0; r < 4; ++r) {
            acc[g][mt][r] += pl[w][g][mt][q * 4 + r][n];
            pl[w][g][mt][q * 4 + r][n] = acc[g][mt][r];
          }
    }
    __syncthreads();
    {  // final 4-way reduce: 2048 sums, 4 per thread (vectorized)
      int base = tid * 4;
      int col = base & 15, row = (base >> 4) & 15, mt = (base >> 8) & 1, g = base >> 9;
      floatx4 s = *(const floatx4*)&pl[0][g][mt][row][col];
      s += *(const floatx4*)&pl[1][g][mt][row][col];
      s += *(const floatx4*)&pl[2][g][mt][row][col];
      s += *(const floatx4*)&pl[3][g][mt][row][col];
      *(floatx4*)&red[g][mt][row][col] = s;
    }
    __syncthreads();
    {  // cell update (c in register)
      float gi = sigf(red[0][mtc][rowc][u_l] + b0);
      float gf = sigf(red[1][mtc][rowc][u_l] + b1);
      float gg = tanhfast(red[2][mtc][rowc][u_l] + b2);
      float go = sigf(red[3][mtc][rowc][u_l] + b3);
      float cv = gf * creg + gi * gg;
      creg = cv;
      float hv = go * tanhfast(cv);
      hout[hidx] = (_Float16)hv;
      encPtr[0] = hv;
      encPtr += HH;
    }
    grid_barrier(bar, ++barIdx);
  }

  // ================= decoder =================
  {  // step-1 weights (inp == h_n -> Wih+Whh, precomputed)
    const _Float16* base = decW1 + (size_t)(u0 + n) * HH + (size_t)(kh0 + q * 8);
#pragma unroll
    for (int g = 0; g < 4; ++g)
#pragma unroll
      for (int kk = 0; kk < 4; ++kk)
        bw[g][kk] = *(const half8*)(base + (size_t)g * ((size_t)HH * HH) + kk * 32);
  }
  b0 = decB1[cu]; b1 = decB1[HH + cu]; b2 = decB1[2 * HH + cu]; b3 = decB1[3 * HH + cu];

  half8 ow[4];               // out_W fragments for y_{s-1} (ut<8 blocks only)
  if (ut < 8) {
    const _Float16* oro = outW + (size_t)(u0 + n) * HH + (size_t)(kh0 + q * 8);
#pragma unroll
    for (int kk = 0; kk < 4; ++kk) ow[kk] = *(const half8*)(oro + kk * 32);
  }
  const float obv_cu = (ut < 8) ? oB[cu] : 0.0f;

  for (int s = 1; s <= SS; ++s) {
    if (s == 2) {  // switch to W2 = dec_Whh + dec_Wih[:,:D]@out_W (y-feedback folded)
      const _Float16* base = decW2 + (size_t)(u0 + n) * HH + (size_t)(kh0 + q * 8);
#pragma unroll
      for (int g = 0; g < 4; ++g)
#pragma unroll
        for (int kk = 0; kk < 4; ++kk)
          bw[g][kk] = *(const half8*)(base + (size_t)g * ((size_t)HH * HH) + kk * 32);
      b0 = decB2[cu]; b1 = decB2[HH + cu]; b2 = decB2[2 * HH + cu]; b3 = decB2[3 * HH + cu];
    }
    const int p = 511 + s;   // global step parity (continues encoder chain)
    const _Float16* h0 = (p & 1) ? hrowB : hrowA;
    _Float16* hout = (p & 1) ? hA : hB;
    const _Float16* h1 = h0 + (size_t)16 * HH;
    const bool doY = (s >= 2) && (ut < 8);  // y_{s-1} = h_{s-1} @ out_W.T

    floatx4 acc[4][2];
#pragma unroll
    for (int g = 0; g < 4; ++g) {
      acc[g][0] = (floatx4){0, 0, 0, 0};
      acc[g][1] = (floatx4){0, 0, 0, 0};
    }
    floatx4 accY[2];
    accY[0] = (floatx4){0, 0, 0, 0}; accY[1] = (floatx4){0, 0, 0, 0};

#pragma unroll
    for (int kk = 0; kk < 4; ++kk) {
      half8 a0 = *(const half8*)(h0 + kk * 32);
      half8 a1 = *(const half8*)(h1 + kk * 32);
      acc[0][0] = MFMA16(a0, bw[0][kk], acc[0][0]); acc[0][1] = MFMA16(a1, bw[0][kk], acc[0][1]);
      acc[1][0] = MFMA16(a0, bw[1][kk], acc[1][0]); acc[1][1] = MFMA16(a1, bw[1][kk], acc[1][1]);
      acc[2][0] = MFMA16(a0, bw[2][kk], acc[2][0]); acc[2][1] = MFMA16(a1, bw[2][kk], acc[2][1]);
      acc[3][0] = MFMA16(a0, bw[3][kk], acc[3][0]); acc[3][1] = MFMA16(a1, bw[3][kk], acc[3][1]);
      if (doY) {
        accY[0] = MFMA16(a0, ow[kk], accY[0]);
        accY[1] = MFMA16(a1, ow[kk], accY[1]);
      }
    }

    if (w >= 4) {
#pragma unroll
      for (int g = 0; g < 4; ++g)
#pragma unroll
        for (int mt = 0; mt < 2; ++mt)
#pragma unroll
          for (int r = 0; r < 4; ++r)
            pl[w - 4][g][mt][q * 4 + r][n] = acc[g][mt][r];
      if (doY)
#pragma unroll
        for (int mt = 0; mt < 2; ++mt)
#pragma unroll
          for (int r = 0; r < 4; ++r)
            pY[w - 4][mt][q * 4 + r][n] = accY[mt][r];
    }
    __syncthreads();
    if (w < 4) {
#pragma unroll
      for (int g = 0; g < 4; ++g)
#pragma unroll
        for (int mt = 0; mt < 2; ++mt)
#pragma unroll
          for (int r = 0; r < 4; ++r) {
            acc[g][mt][r] += pl[w][g][mt][q * 4 + r][n];
            pl[w][g][mt][q * 4 + r][n] = acc[g][mt][r];
          }
      if (doY)
#pragma unroll
        for (int mt = 0; mt < 2; ++mt)
#pragma unroll
          for (int r = 0; r < 4; ++r) {
            accY[mt][r] += pY[w][mt][q * 4 + r][n];
            pY[w][mt][q * 4 + r][n] = accY[mt][r];
          }
    }
    __syncthreads();
    {
      int base = tid * 4;
      int col = base & 15, row = (base >> 4) & 15, mt = (base >> 8) & 1, g = base >> 9;
      floatx4 sv = *(const floatx4*)&pl[0][g][mt][row][col];
      sv += *(const floatx4*)&pl[1][g][mt][row][col];
      sv += *(const floatx4*)&pl[2][g][mt][row][col];
      sv += *(const floatx4*)&pl[3][g][mt][row][col];
      *(floatx4*)&red[g][mt][row][col] = sv;
    }
    if (doY && tid < 128) {
      int base = tid * 4;
      int col = base & 15, row = (base >> 4) & 15, mt = (base >> 8) & 1;
      floatx4 sv = *(const floatx4*)&pY[0][mt][row][col];
      sv += *(const floatx4*)&pY[1][mt][row][col];
      sv += *(const floatx4*)&pY[2][mt][row][col];
      sv += *(const floatx4*)&pY[3][mt][row][col];
      *(floatx4*)&redY[mt][row][col] = sv;
    }
    __syncthreads();
    {
      float gi = sigf(red[0][mtc][rowc][u_l] + b0);
      float gf = sigf(red[1][mtc][rowc][u_l] + b1);
      float gg = tanhfast(red[2][mtc][rowc][u_l] + b2);
      float go = sigf(red[3][mtc][rowc][u_l] + b3);
      float cv = gf * creg + gi * gg;
      creg = cv;
      float hv = go * tanhfast(cv);
      hout[hidx] = (_Float16)hv;
      if (doY) {
        int ty = s - 2;
        float yv = redY[mtc][rowc][u_l] + obv_cu;
        size_t ix = (size_t)cm * ((size_t)SS * DD) + (size_t)ty * DD + cu;
        recon[ix] = yv;
        float e = yv - x[ix];
        float ls = e * e;
#pragma unroll
        for (int off = 32; off; off >>= 1) ls += __shfl_xor(ls, off, 64);
        if (lane == 0) atomicAdd(lossAcc, ls);
      }
    }
    grid_barrier(bar, ++barIdx);
  }

  // ---- final y (recon[:,511]) from final h (parity: p=1023 wrote hA) ----
  if ((int)blockIdx.x < 64 && tid < 64) {
    const int fmt = (int)blockIdx.x >> 3, fdt = (int)blockIdx.x & 7;
    const int fm0 = fmt << 4, d0 = fdt << 4;
    floatx4 a4 = (floatx4){0, 0, 0, 0};
    const _Float16* hrow = hA + (size_t)(fm0 + n) * HH;
    const _Float16* orow = outW + (size_t)(d0 + n) * HH;
    for (int kI = 0; kI < 32; ++kI) {
      int k0 = kI * 32 + q * 8;
      a4 = MFMA16(*(const half8*)(hrow + k0), *(const half8*)(orow + k0), a4);
    }
    int d = d0 + n;
    float ob2 = oB[d];
    float ls = 0.0f;
#pragma unroll
    for (int r = 0; r < 4; ++r) {
      int m = fm0 + q * 4 + r;
      float yv = a4[r] + ob2;
      size_t ix = (size_t)m * ((size_t)SS * DD) + (size_t)(SS - 1) * DD + d;
      recon[ix] = yv;
      float e = yv - x[ix];
      ls += e * e;
    }
#pragma unroll
    for (int off = 32; off; off >>= 1) ls += __shfl_xor(ls, off, 64);
    if (lane == 0) atomicAdd(lossAcc, ls);
  }
  grid_barrier(bar, ++barIdx);
  if (blockIdx.x == 0 && tid == 0)
    lossOut[0] = __hip_atomic_load(lossAcc, __ATOMIC_ACQUIRE, __HIP_MEMORY_SCOPE_AGENT) *
                 (1.0f / (float)BB);
}

// ---- host -------------------------------------------------------------------

extern "C" void kernel_launch(void* const* d_in, const int* in_sizes, int n_in,
                              void* d_out, int out_size, void* d_ws, size_t ws_size,
                              hipStream_t stream) {
  const float* x    = (const float*)d_in[0];
  const float* eWih = (const float*)d_in[1];
  const float* eWhh = (const float*)d_in[2];
  const float* eBih = (const float*)d_in[3];
  const float* eBhh = (const float*)d_in[4];
  const float* dWih = (const float*)d_in[5];
  const float* dWhh = (const float*)d_in[6];
  const float* dBih = (const float*)d_in[7];
  const float* dBhh = (const float*)d_in[8];
  const float* oW   = (const float*)d_in[9];
  const float* oB   = (const float*)d_in[10];

  float* out = (float*)d_out;
  float* recon = out;                                   // (B,S,D)
  float* encOut = out + (size_t)BB * SS * DD;           // (B,S,H)
  float* lossOut = out + (size_t)BB * SS * DD + (size_t)BB * SS * HH;  // scalar

  char* p = (char*)d_ws;
  auto alloc = [&](size_t bytes) {
    char* r = p;
    p += (bytes + 255) & ~(size_t)255;
    return r;
  };
  _Float16* encW   = (_Float16*)alloc((size_t)G4 * KENC * 2);  // [Wih|Whh] fp16
  _Float16* decW1  = (_Float16*)alloc((size_t)G4 * HH * 2);
  _Float16* decW2  = (_Float16*)alloc((size_t)G4 * HH * 2);
  _Float16* outW16 = (_Float16*)alloc((size_t)DD * HH * 2);
  float* encB  = (float*)alloc((size_t)G4 * 4);
  float* decB1 = (float*)alloc((size_t)G4 * 4);
  float* decB2 = (float*)alloc((size_t)G4 * 4);
  _Float16* hA = (_Float16*)alloc((size_t)BB * HH * 2);
  _Float16* hB = (_Float16*)alloc((size_t)BB * HH * 2);
  float* lossAcc = (float*)alloc(256);
  unsigned* bar = (unsigned*)alloc(256);
  (void)in_sizes; (void)n_in; (void)out_size; (void)ws_size;

  k_prep_encw<<<G4, 256, 0, stream>>>(eWih, eWhh, encW);
  k_prep_simple<<<2048, 256, 0, stream>>>(dWih, dWhh, oW, eBih, eBhh, dBih, dBhh, oB,
                                          decW1, outW16, encB, decB1, decB2, hA, lossAcc, bar);
  k_prep_decw2<<<G4 * 4, 256, 0, stream>>>(dWih, dWhh, oW, decW2);

  void* args[] = {(void*)&x, (void*)&encW, (void*)&encB, (void*)&decW1, (void*)&decW2,
                  (void*)&decB1, (void*)&decB2, (void*)&outW16, (void*)&oB,
                  (void*)&hA, (void*)&hB, (void*)&encOut, (void*)&recon,
                  (void*)&lossAcc, (void*)&lossOut, (void*)&bar};
  (void)hipLaunchCooperativeKernel((void*)k_seq, dim3(NBLK), dim3(512), args, 0, stream);
}

// Round 2
// 14261.958 us; speedup vs baseline: 2.4796x; 2.4796x over previous
//
#include <hip/hip_runtime.h>

// LSTM autoencoder, MI355X. Round 4: persistent cooperative kernel with
// minimal-coherence grid barrier. Round-3 post-mortem: per-poll ACQUIRE loads
// each emitted buffer_inv (L2 invalidate) -> 255 blocks spamming L2 invs =
// 34us/step, MfmaUtil 1.3%. Fix: relaxed poll + exactly one release fence
// (wbl2) before arrival and one acquire fence (inv) after, monotonic
// generation flag (no reset hazard), counter/flag on separate cache lines.
// Also pad LDS reduce rows 16->20 floats (4-way bank conflict -> free 2-way).

#define BB 128
#define SS 512
#define DD 128
#define HH 1024
#define G4 4096
#define KENC 1152
#define NBLK 256
#define RP 20   // padded row width (floats) for LDS reduce tiles

typedef _Float16 half8 __attribute__((ext_vector_type(8)));
typedef float floatx4 __attribute__((ext_vector_type(4)));

__device__ __forceinline__ float sigf(float x) { return 1.0f / (1.0f + __expf(-x)); }
__device__ __forceinline__ float tanhfast(float x) { return 1.0f - 2.0f / (1.0f + __expf(2.0f * x)); }

#define MFMA16(a, b, c) __builtin_amdgcn_mfma_f32_16x16x32_f16((a), (b), (c), 0, 0, 0)

// ---- prep kernels -----------------------------------------------------------

__global__ void k_prep_encw(const float* __restrict__ eWih, const float* __restrict__ eWhh,
                            _Float16* __restrict__ encW) {
  int r = blockIdx.x;  // 0..4095
  for (int k = threadIdx.x; k < KENC; k += blockDim.x) {
    float v = (k < DD) ? eWih[(size_t)r * DD + k] : eWhh[(size_t)r * HH + (k - DD)];
    encW[(size_t)r * KENC + k] = (_Float16)v;
  }
}

__global__ void k_prep_simple(const float* __restrict__ dWih, const float* __restrict__ dWhh,
                              const float* __restrict__ oW,
                              const float* __restrict__ eBih, const float* __restrict__ eBhh,
                              const float* __restrict__ dBih, const float* __restrict__ dBhh,
                              const float* __restrict__ oB,
                              _Float16* __restrict__ decW1, _Float16* __restrict__ outW16,
                              float* __restrict__ encB, float* __restrict__ decB1,
                              float* __restrict__ decB2,
                              _Float16* __restrict__ hA, float* __restrict__ lossAcc,
                              unsigned* __restrict__ bar) {
  int tid = blockIdx.x * blockDim.x + threadIdx.x;
  int nt = gridDim.x * blockDim.x;
  for (size_t i = tid; i < (size_t)G4 * HH; i += nt)
    decW1[i] = (_Float16)(dWih[i] + dWhh[i]);   // dec step1: inp==h_n -> Wih+Whh
  for (size_t i = tid; i < (size_t)DD * HH; i += nt)
    outW16[i] = (_Float16)oW[i];
  for (size_t i = tid; i < (size_t)BB * HH; i += nt)
    hA[i] = (_Float16)0.0f;
  if (tid == 0) { lossAcc[0] = 0.0f; bar[0] = 0u; bar[64] = 0u; }
  if (tid < G4) {
    encB[tid] = eBih[tid] + eBhh[tid];
    float b1 = dBih[tid] + dBhh[tid];
    decB1[tid] = b1;
    float acc = b1;  // b2 = b1 + dec_Wih[:,:D] @ out_b
    for (int j = 0; j < DD; ++j) acc += dWih[(size_t)tid * HH + j] * oB[j];
    decB2[tid] = acc;
  }
}

// W2 = dec_Whh + dec_Wih[:,:D] @ out_W   (4096 x 1024)
__global__ void k_prep_decw2(const float* __restrict__ dWih, const float* __restrict__ dWhh,
                             const float* __restrict__ oW, _Float16* __restrict__ decW2) {
  int r = blockIdx.x >> 2;                       // 0..4095
  int c = ((blockIdx.x & 3) << 8) + threadIdx.x; // 0..1023
  float acc = dWhh[(size_t)r * HH + c];
  for (int j = 0; j < DD; ++j) acc += dWih[(size_t)r * HH + j] * oW[(size_t)j * HH + c];
  decW2[(size_t)r * HH + c] = (_Float16)acc;
}

// ---- grid barrier -----------------------------------------------------------
// Monotonic generation: at barrier #step, total arrivals reach step*NBLK; last
// arriver publishes flag=step (relaxed — no reset ordering hazard since nothing
// is reset). Pollers use RELAXED agent loads (bypass L2 to coherence point, NO
// buffer_inv per poll — that was Round 3's 34us/step bug). Exactly one release
// fence (wbl2: h stores -> coherence point) before arrival and one acquire
// fence (inv: drop stale L2 h lines) after detection, per block per step.
// arrive and flag sit 256B apart so polls don't collide with the RMW line.
__device__ __forceinline__ void grid_barrier(unsigned* arrive, unsigned* flag, unsigned step) {
  __syncthreads();  // compiler emits s_waitcnt vmcnt(0) before s_barrier: all
                    // threads' h stores are in L2 before thread0 fences
  if (threadIdx.x == 0) {
    __builtin_amdgcn_fence(__ATOMIC_RELEASE, "agent");   // wbl2 (once)
    unsigned old = __hip_atomic_fetch_add(arrive, 1u, __ATOMIC_RELAXED, __HIP_MEMORY_SCOPE_AGENT);
    if (old == step * NBLK - 1u) {
      __hip_atomic_store(flag, step, __ATOMIC_RELAXED, __HIP_MEMORY_SCOPE_AGENT);
    } else {
      while (__hip_atomic_load(flag, __ATOMIC_RELAXED, __HIP_MEMORY_SCOPE_AGENT) < step)
        __builtin_amdgcn_s_sleep(1);
    }
    __builtin_amdgcn_fence(__ATOMIC_ACQUIRE, "agent");   // inv (once)
  }
  __syncthreads();
}

// ---- persistent sequence kernel --------------------------------------------
// Grid 256 = (mtb 0..3)<<6 | (ut 0..63); 512 threads = 8 waves (K-split).
// MFMA 16x16x32_f16: A[m=lane&15][k=(lane>>4)*8+j], B[n=lane&15][k=...],
// C/D: row=(lane>>4)*4+reg, col=lane&15.

__global__ __launch_bounds__(512, 2) void k_seq(
    const float* __restrict__ x, const _Float16* __restrict__ encW,
    const float* __restrict__ encB,
    const _Float16* __restrict__ decW1, const _Float16* __restrict__ decW2,
    const float* __restrict__ decB1, const float* __restrict__ decB2,
    const _Float16* __restrict__ outW, const float* __restrict__ oB,
    _Float16* __restrict__ hA, _Float16* __restrict__ hB,
    float* __restrict__ encOut, float* __restrict__ recon,
    float* __restrict__ lossAcc, float* __restrict__ lossOut,
    unsigned* __restrict__ bar) {
  // rows padded to RP=20 floats (80B, 16B-aligned): bank=(20*row+n)%32 varies
  // with q-group -> write/read conflicts drop from 4-way to the free 2-way.
  __shared__ float pl[4][4][2][16][RP];   // [slot][gate][mtile][row][col] 40 KB
  __shared__ float red[4][2][16][RP];     // 10 KB
  __shared__ float pY[4][2][16][RP];      // 10 KB
  __shared__ float redY[2][16][RP];       // 2.5 KB

  const int tid = threadIdx.x;
  const int lane = tid & 63, w = tid >> 6;
  const int n = lane & 15, q = lane >> 4;
  const int ut = (int)blockIdx.x & 63, mtb = (int)blockIdx.x >> 6;
  const int m0 = mtb << 5, u0 = ut << 4;
  const int kh0 = w << 7;   // this wave's 128-wide K slice of the h part

  // step-invariant cell-update mapping: thread tid -> (m_l = tid>>4, u_l = tid&15)
  const int m_l = tid >> 4, u_l = tid & 15;
  const int mtc = m_l >> 4, rowc = m_l & 15;
  const int cm = m0 + m_l, cu = u0 + u_l;
  const size_t hidx = (size_t)cm * HH + cu;

  unsigned* barArr = bar;
  unsigned* barFlag = bar + 64;
  unsigned barIdx = 0;
  float creg = 0.0f;        // cell state c[cm][cu] lives here for all 1024 steps

  // -------- encoder weights -> registers (loop-invariant) --------
  half8 bw[4][4];           // [gate][kk] : 64 VGPR
  half8 xw[4];              // x-part fragments (waves 0..3 only) : 16 VGPR
  {
    const _Float16* base = encW + (size_t)(u0 + n) * KENC + (size_t)(DD + kh0 + q * 8);
#pragma unroll
    for (int g = 0; g < 4; ++g)
#pragma unroll
      for (int kk = 0; kk < 4; ++kk)
        bw[g][kk] = *(const half8*)(base + (size_t)g * ((size_t)HH * KENC) + kk * 32);
    if (w < 4) {
      const _Float16* xb = encW + (size_t)(u0 + n) * KENC + (size_t)((w << 5) + q * 8);
#pragma unroll
      for (int g = 0; g < 4; ++g)
        xw[g] = *(const half8*)(xb + (size_t)g * ((size_t)HH * KENC));
    }
  }
  float b0 = encB[cu], b1 = encB[HH + cu], b2 = encB[2 * HH + cu], b3 = encB[3 * HH + cu];

  // step-invariant pointers
  const _Float16* hrowA = hA + (size_t)(m0 + n) * HH + kh0 + q * 8;
  const _Float16* hrowB = hB + (size_t)(m0 + n) * HH + kh0 + q * 8;
  const float* xr0base = x + (size_t)(m0 + n) * ((size_t)SS * DD) + (size_t)((w << 5) + q * 8);
  const float* xr1base = xr0base + (size_t)16 * ((size_t)SS * DD);
  float* encPtr = encOut + (size_t)cm * ((size_t)SS * HH) + cu;

  // ================= encoder =================
  for (int t = 0; t < SS; ++t) {
    const _Float16* h0 = (t & 1) ? hrowB : hrowA;
    _Float16* hout = (t & 1) ? hA : hB;
    const _Float16* h1 = h0 + (size_t)16 * HH;

    floatx4 acc[4][2];
#pragma unroll
    for (int g = 0; g < 4; ++g) {
      acc[g][0] = (floatx4){0, 0, 0, 0};
      acc[g][1] = (floatx4){0, 0, 0, 0};
    }
#pragma unroll
    for (int kk = 0; kk < 4; ++kk) {
      half8 a0 = *(const half8*)(h0 + kk * 32);
      half8 a1 = *(const half8*)(h1 + kk * 32);
      acc[0][0] = MFMA16(a0, bw[0][kk], acc[0][0]); acc[0][1] = MFMA16(a1, bw[0][kk], acc[0][1]);
      acc[1][0] = MFMA16(a0, bw[1][kk], acc[1][0]); acc[1][1] = MFMA16(a1, bw[1][kk], acc[1][1]);
      acc[2][0] = MFMA16(a0, bw[2][kk], acc[2][0]); acc[2][1] = MFMA16(a1, bw[2][kk], acc[2][1]);
      acc[3][0] = MFMA16(a0, bw[3][kk], acc[3][0]); acc[3][1] = MFMA16(a1, bw[3][kk], acc[3][1]);
    }
    if (w < 4) {  // waves 0..3 take the x part (K=128, 32 each)
      const float* xr0 = xr0base + (size_t)t * DD;
      const float* xr1 = xr1base + (size_t)t * DD;
      floatx4 p0 = *(const floatx4*)xr0;
      floatx4 p1 = *(const floatx4*)(xr0 + 4);
      floatx4 p2 = *(const floatx4*)xr1;
      floatx4 p3 = *(const floatx4*)(xr1 + 4);
      half8 a0, a1;
#pragma unroll
      for (int j = 0; j < 4; ++j) {
        a0[j] = (_Float16)p0[j]; a0[j + 4] = (_Float16)p1[j];
        a1[j] = (_Float16)p2[j]; a1[j + 4] = (_Float16)p3[j];
      }
      acc[0][0] = MFMA16(a0, xw[0], acc[0][0]); acc[0][1] = MFMA16(a1, xw[0], acc[0][1]);
      acc[1][0] = MFMA16(a0, xw[1], acc[1][0]); acc[1][1] = MFMA16(a1, xw[1], acc[1][1]);
      acc[2][0] = MFMA16(a0, xw[2], acc[2][0]); acc[2][1] = MFMA16(a1, xw[2], acc[2][1]);
      acc[3][0] = MFMA16(a0, xw[3], acc[3][0]); acc[3][1] = MFMA16(a1, xw[3], acc[3][1]);
    }

    // 2-level reduction tree over the 8 K-slices
    if (w >= 4) {
#pragma unroll
      for (int g = 0; g < 4; ++g)
#pragma unroll
        for (int mt = 0; mt < 2; ++mt)
#pragma unroll
          for (int r = 0; r < 4; ++r)
            pl[w - 4][g][mt][q * 4 + r][n] = acc[g][mt][r];
    }
    __syncthreads();
    if (w < 4) {
#pragma unroll
      for (int g = 0; g < 4; ++g)
#pragma unroll
        for (int mt = 0; mt < 2; ++mt)
#pragma unroll
          for (int r = 0; r < 4; ++r) {
            acc[g][mt][r] += pl[w][g][mt][q * 4 + r][n];
            pl[w][g][mt][q * 4 + r][n] = acc[g][mt][r];
          }
    }
    __syncthreads();
    {  // final 4-way reduce: 2048 sums, 4 per thread (vectorized)
      int base = tid * 4;
      int col = base & 15, row = (base >> 4) & 15, mt = (base >> 8) & 1, g = base >> 9;
      floatx4 s = *(const floatx4*)&pl[0][g][mt][row][col];
      s += *(const floatx4*)&pl[1][g][mt][row][col];
      s += *(const floatx4*)&pl[2][g][mt][row][col];
      s += *(const floatx4*)&pl[3][g][mt][row][col];
      *(floatx4*)&red[g][mt][row][col] = s;
    }
    __syncthreads();
    {  // cell update (c in register)
      float gi = sigf(red[0][mtc][rowc][u_l] + b0);
      float gf = sigf(red[1][mtc][rowc][u_l] + b1);
      float gg = tanhfast(red[2][mtc][rowc][u_l] + b2);
      float go = sigf(red[3][mtc][rowc][u_l] + b3);
      float cv = gf * creg + gi * gg;
      creg = cv;
      float hv = go * tanhfast(cv);
      hout[hidx] = (_Float16)hv;
      encPtr[0] = hv;
      encPtr += HH;
    }
    grid_barrier(barArr, barFlag, ++barIdx);
  }

  // ================= decoder =================
  {  // step-1 weights (inp == h_n -> Wih+Whh, precomputed)
    const _Float16* base = decW1 + (size_t)(u0 + n) * HH + (size_t)(kh0 + q * 8);
#pragma unroll
    for (int g = 0; g < 4; ++g)
#pragma unroll
      for (int kk = 0; kk < 4; ++kk)
        bw[g][kk] = *(const half8*)(base + (size_t)g * ((size_t)HH * HH) + kk * 32);
  }
  b0 = decB1[cu]; b1 = decB1[HH + cu]; b2 = decB1[2 * HH + cu]; b3 = decB1[3 * HH + cu];

  half8 ow[4];               // out_W fragments for y_{s-1} (ut<8 blocks only)
  if (ut < 8) {
    const _Float16* oro = outW + (size_t)(u0 + n) * HH + (size_t)(kh0 + q * 8);
#pragma unroll
    for (int kk = 0; kk < 4; ++kk) ow[kk] = *(const half8*)(oro + kk * 32);
  }
  const float obv_cu = (ut < 8) ? oB[cu] : 0.0f;

  for (int s = 1; s <= SS; ++s) {
    if (s == 2) {  // switch to W2 = dec_Whh + dec_Wih[:,:D]@out_W (y-feedback folded)
      const _Float16* base = decW2 + (size_t)(u0 + n) * HH + (size_t)(kh0 + q * 8);
#pragma unroll
      for (int g = 0; g < 4; ++g)
#pragma unroll
        for (int kk = 0; kk < 4; ++kk)
          bw[g][kk] = *(const half8*)(base + (size_t)g * ((size_t)HH * HH) + kk * 32);
      b0 = decB2[cu]; b1 = decB2[HH + cu]; b2 = decB2[2 * HH + cu]; b3 = decB2[3 * HH + cu];
    }
    const int p = 511 + s;   // global step parity (continues encoder chain)
    const _Float16* h0 = (p & 1) ? hrowB : hrowA;
    _Float16* hout = (p & 1) ? hA : hB;
    const _Float16* h1 = h0 + (size_t)16 * HH;
    const bool doY = (s >= 2) && (ut < 8);  // y_{s-1} = h_{s-1} @ out_W.T

    floatx4 acc[4][2];
#pragma unroll
    for (int g = 0; g < 4; ++g) {
      acc[g][0] = (floatx4){0, 0, 0, 0};
      acc[g][1] = (floatx4){0, 0, 0, 0};
    }
    floatx4 accY[2];
    accY[0] = (floatx4){0, 0, 0, 0}; accY[1] = (floatx4){0, 0, 0, 0};

#pragma unroll
    for (int kk = 0; kk < 4; ++kk) {
      half8 a0 = *(const half8*)(h0 + kk * 32);
      half8 a1 = *(const half8*)(h1 + kk * 32);
      acc[0][0] = MFMA16(a0, bw[0][kk], acc[0][0]); acc[0][1] = MFMA16(a1, bw[0][kk], acc[0][1]);
      acc[1][0] = MFMA16(a0, bw[1][kk], acc[1][0]); acc[1][1] = MFMA16(a1, bw[1][kk], acc[1][1]);
      acc[2][0] = MFMA16(a0, bw[2][kk], acc[2][0]); acc[2][1] = MFMA16(a1, bw[2][kk], acc[2][1]);
      acc[3][0] = MFMA16(a0, bw[3][kk], acc[3][0]); acc[3][1] = MFMA16(a1, bw[3][kk], acc[3][1]);
      if (doY) {
        accY[0] = MFMA16(a0, ow[kk], accY[0]);
        accY[1] = MFMA16(a1, ow[kk], accY[1]);
      }
    }

    if (w >= 4) {
#pragma unroll
      for (int g = 0; g < 4; ++g)
#pragma unroll
        for (int mt = 0; mt < 2; ++mt)
#pragma unroll
          for (int r = 0; r < 4; ++r)
            pl[w - 4][g][mt][q * 4 + r][n] = acc[g][mt][r];
      if (doY)
#pragma unroll
        for (int mt = 0; mt < 2; ++mt)
#pragma unroll
          for (int r = 0; r < 4; ++r)
            pY[w - 4][mt][q * 4 + r][n] = accY[mt][r];
    }
    __syncthreads();
    if (w < 4) {
#pragma unroll
      for (int g = 0; g < 4; ++g)
#pragma unroll
        for (int mt = 0; mt < 2; ++mt)
#pragma unroll
          for (int r = 0; r < 4; ++r) {
            acc[g][mt][r] += pl[w][g][mt][q * 4 + r][n];
            pl[w][g][mt][q * 4 + r][n] = acc[g][mt][r];
          }
      if (doY)
#pragma unroll
        for (int mt = 0; mt < 2; ++mt)
#pragma unroll
          for (int r = 0; r < 4; ++r) {
            accY[mt][r] += pY[w][mt][q * 4 + r][n];
            pY[w][mt][q * 4 + r][n] = accY[mt][r];
          }
    }
    __syncthreads();
    {
      int base = tid * 4;
      int col = base & 15, row = (base >> 4) & 15, mt = (base >> 8) & 1, g = base >> 9;
      floatx4 sv = *(const floatx4*)&pl[0][g][mt][row][col];
      sv += *(const floatx4*)&pl[1][g][mt][row][col];
      sv += *(const floatx4*)&pl[2][g][mt][row][col];
      sv += *(const floatx4*)&pl[3][g][mt][row][col];
      *(floatx4*)&red[g][mt][row][col] = sv;
    }
    if (doY && tid < 128) {
      int base = tid * 4;
      int col = base & 15, row = (base >> 4) & 15, mt = (base >> 8) & 1;
      floatx4 sv = *(const floatx4*)&pY[0][mt][row][col];
      sv += *(const floatx4*)&pY[1][mt][row][col];
      sv += *(const floatx4*)&pY[2][mt][row][col];
      sv += *(const floatx4*)&pY[3][mt][row][col];
      *(floatx4*)&redY[mt][row][col] = sv;
    }
    __syncthreads();
    {
      float gi = sigf(red[0][mtc][rowc][u_l] + b0);
      float gf = sigf(red[1][mtc][rowc][u_l] + b1);
      float gg = tanhfast(red[2][mtc][rowc][u_l] + b2);
      float go = sigf(red[3][mtc][rowc][u_l] + b3);
      float cv = gf * creg + gi * gg;
      creg = cv;
      float hv = go * tanhfast(cv);
      hout[hidx] = (_Float16)hv;
      if (doY) {
        int ty = s - 2;
        float yv = redY[mtc][rowc][u_l] + obv_cu;
        size_t ix = (size_t)cm * ((size_t)SS * DD) + (size_t)ty * DD + cu;
        recon[ix] = yv;
        float e = yv - x[ix];
        float ls = e * e;
#pragma unroll
        for (int off = 32; off; off >>= 1) ls += __shfl_xor(ls, off, 64);
        if (lane == 0) atomicAdd(lossAcc, ls);
      }
    }
    grid_barrier(barArr, barFlag, ++barIdx);
  }

  // ---- final y (recon[:,511]) from final h (parity: p=1023 wrote hA) ----
  if ((int)blockIdx.x < 64 && tid < 64) {
    const int fmt = (int)blockIdx.x >> 3, fdt = (int)blockIdx.x & 7;
    const int fm0 = fmt << 4, d0 = fdt << 4;
    floatx4 a4 = (floatx4){0, 0, 0, 0};
    const _Float16* hrow = hA + (size_t)(fm0 + n) * HH;
    const _Float16* orow = outW + (size_t)(d0 + n) * HH;
    for (int kI = 0; kI < 32; ++kI) {
      int k0 = kI * 32 + q * 8;
      a4 = MFMA16(*(const half8*)(hrow + k0), *(const half8*)(orow + k0), a4);
    }
    int d = d0 + n;
    float ob2 = oB[d];
    float ls = 0.0f;
#pragma unroll
    for (int r = 0; r < 4; ++r) {
      int m = fm0 + q * 4 + r;
      float yv = a4[r] + ob2;
      size_t ix = (size_t)m * ((size_t)SS * DD) + (size_t)(SS - 1) * DD + d;
      recon[ix] = yv;
      float e = yv - x[ix];
      ls += e * e;
    }
#pragma unroll
    for (int off = 32; off; off >>= 1) ls += __shfl_xor(ls, off, 64);
    if (lane == 0) atomicAdd(lossAcc, ls);
  }
  grid_barrier(barArr, barFlag, ++barIdx);
  if (blockIdx.x == 0 && tid == 0)
    lossOut[0] = __hip_atomic_load(lossAcc, __ATOMIC_ACQUIRE, __HIP_MEMORY_SCOPE_AGENT) *
                 (1.0f / (float)BB);
}

// ---- host -------------------------------------------------------------------

extern "C" void kernel_launch(void* const* d_in, const int* in_sizes, int n_in,
                              void* d_out, int out_size, void* d_ws, size_t ws_size,
                              hipStream_t stream) {
  const float* x    = (const float*)d_in[0];
  const float* eWih = (const float*)d_in[1];
  const float* eWhh = (const float*)d_in[2];
  const float* eBih = (const float*)d_in[3];
  const float* eBhh = (const float*)d_in[4];
  const float* dWih = (const float*)d_in[5];
  const float* dWhh = (const float*)d_in[6];
  const float* dBih = (const float*)d_in[7];
  const float* dBhh = (const float*)d_in[8];
  const float* oW   = (const float*)d_in[9];
  const float* oB   = (const float*)d_in[10];

  float* out = (float*)d_out;
  float* recon = out;                                   // (B,S,D)
  float* encOut = out + (size_t)BB * SS * DD;           // (B,S,H)
  float* lossOut = out + (size_t)BB * SS * DD + (size_t)BB * SS * HH;  // scalar

  char* p = (char*)d_ws;
  auto alloc = [&](size_t bytes) {
    char* r = p;
    p += (bytes + 255) & ~(size_t)255;
    return r;
  };
  _Float16* encW   = (_Float16*)alloc((size_t)G4 * KENC * 2);  // [Wih|Whh] fp16
  _Float16* decW1  = (_Float16*)alloc((size_t)G4 * HH * 2);
  _Float16* decW2  = (_Float16*)alloc((size_t)G4 * HH * 2);
  _Float16* outW16 = (_Float16*)alloc((size_t)DD * HH * 2);
  float* encB  = (float*)alloc((size_t)G4 * 4);
  float* decB1 = (float*)alloc((size_t)G4 * 4);
  float* decB2 = (float*)alloc((size_t)G4 * 4);
  _Float16* hA = (_Float16*)alloc((size_t)BB * HH * 2);
  _Float16* hB = (_Float16*)alloc((size_t)BB * HH * 2);
  float* lossAcc = (float*)alloc(256);
  unsigned* bar = (unsigned*)alloc(512);
  (void)in_sizes; (void)n_in; (void)out_size; (void)ws_size;

  k_prep_encw<<<G4, 256, 0, stream>>>(eWih, eWhh, encW);
  k_prep_simple<<<2048, 256, 0, stream>>>(dWih, dWhh, oW, eBih, eBhh, dBih, dBhh, oB,
                                          decW1, outW16, encB, decB1, decB2, hA, lossAcc, bar);
  k_prep_decw2<<<G4 * 4, 256, 0, stream>>>(dWih, dWhh, oW, decW2);

  void* args[] = {(void*)&x, (void*)&encW, (void*)&encB, (void*)&decW1, (void*)&decW2,
                  (void*)&decB1, (void*)&decB2, (void*)&outW16, (void*)&oB,
                  (void*)&hA, (void*)&hB, (void*)&encOut, (void*)&recon,
                  (void*)&lossAcc, (void*)&lossOut, (void*)&bar};
  (void)hipLaunchCooperativeKernel((void*)k_seq, dim3(NBLK), dim3(512), args, 0, stream);
}

// Round 3
// 6137.136 us; speedup vs baseline: 5.7622x; 2.3239x over previous
//
#include <hip/hip_runtime.h>

// LSTM autoencoder, MI355X. Round 5: persistent cooperative kernel, fence-free
// step exchange. Round-4 post-mortem: 13.5us/step was the barrier machinery —
// 256 serialized same-line RMWs + 256 wbl2 + 256 inv per step (full-L2
// writeback/invalidate, x refetched every step). Fix:
//  * h exchange via sc0 sc1 write-through stores + L2-bypass loads (inline asm)
//    -> NO wbl2/inv anywhere in the loop; L2 stays warm for x16/weights.
//  * barrier: per-block arrival slot (relaxed atomic STORE, no RMW) + direct
//    poll of the 64 slots of the block's mtb-group (only those 64 blocks
//    produce the h rows this block reads). Slots padded to 64B to spread poll
//    traffic across TCC channels. Release = per-wave s_waitcnt vmcnt(0) (write-
//    through acks at coherence point) + __syncthreads before arrival store.
//  * x pre-converted to fp16 (prep); x-part MFMAs issued BEFORE the wait.

#define BB 128
#define SS 512
#define DD 128
#define HH 1024
#define G4 4096
#define KENC 1152
#define NBLK 256
#define RP 20          // padded row width (floats) for LDS reduce tiles
#define SLOTSTRIDE 16  // u32s per barrier slot (64B) -> polls spread over channels

typedef _Float16 half8 __attribute__((ext_vector_type(8)));
typedef float floatx4 __attribute__((ext_vector_type(4)));

__device__ __forceinline__ float sigf(float x) { return 1.0f / (1.0f + __expf(-x)); }
__device__ __forceinline__ float tanhfast(float x) { return 1.0f - 2.0f / (1.0f + __expf(2.0f * x)); }

#define MFMA16(a, b, c) __builtin_amdgcn_mfma_f32_16x16x32_f16((a), (b), (c), 0, 0, 0)

// L2-bypass (system-coherent) 16B load: reads the coherence point, never stale.
__device__ __forceinline__ half8 ldg_h8_sc(const _Float16* p) {
  floatx4 t;
  asm volatile("global_load_dwordx4 %0, %1, off sc0 sc1" : "=v"(t) : "v"(p) : "memory");
  return __builtin_bit_cast(half8, t);
}
// Write-through 2B store: visible at coherence point when vmcnt retires it.
__device__ __forceinline__ void stg_h_sc(_Float16* p, _Float16 v) {
  unsigned u = (unsigned)__builtin_bit_cast(unsigned short, v);
  asm volatile("global_store_short %0, %1, off sc0 sc1" :: "v"(p), "v"(u) : "memory");
}

// ---- prep kernels -----------------------------------------------------------

__global__ void k_prep_encw(const float* __restrict__ eWih, const float* __restrict__ eWhh,
                            _Float16* __restrict__ encW) {
  int r = blockIdx.x;  // 0..4095
  for (int k = threadIdx.x; k < KENC; k += blockDim.x) {
    float v = (k < DD) ? eWih[(size_t)r * DD + k] : eWhh[(size_t)r * HH + (k - DD)];
    encW[(size_t)r * KENC + k] = (_Float16)v;
  }
}

__global__ void k_prep_simple(const float* __restrict__ x, const float* __restrict__ dWih,
                              const float* __restrict__ dWhh, const float* __restrict__ oW,
                              const float* __restrict__ eBih, const float* __restrict__ eBhh,
                              const float* __restrict__ dBih, const float* __restrict__ dBhh,
                              const float* __restrict__ oB,
                              _Float16* __restrict__ x16,
                              _Float16* __restrict__ decW1, _Float16* __restrict__ outW16,
                              float* __restrict__ encB, float* __restrict__ decB1,
                              float* __restrict__ decB2,
                              _Float16* __restrict__ hA, float* __restrict__ lossAcc,
                              unsigned* __restrict__ bar) {
  int tid = blockIdx.x * blockDim.x + threadIdx.x;
  int nt = gridDim.x * blockDim.x;
  for (size_t i = tid; i < (size_t)G4 * HH; i += nt)
    decW1[i] = (_Float16)(dWih[i] + dWhh[i]);   // dec step1: inp==h_n -> Wih+Whh
  for (size_t i = tid; i < (size_t)BB * SS * DD; i += nt)
    x16[i] = (_Float16)x[i];
  for (size_t i = tid; i < (size_t)DD * HH; i += nt)
    outW16[i] = (_Float16)oW[i];
  for (size_t i = tid; i < (size_t)BB * HH; i += nt)
    hA[i] = (_Float16)0.0f;
  for (size_t i = tid; i < (size_t)NBLK * SLOTSTRIDE; i += nt)
    bar[i] = 0u;
  if (tid == 0) lossAcc[0] = 0.0f;
  if (tid < G4) {
    encB[tid] = eBih[tid] + eBhh[tid];
    float b1 = dBih[tid] + dBhh[tid];
    decB1[tid] = b1;
    float acc = b1;  // b2 = b1 + dec_Wih[:,:D] @ out_b
    for (int j = 0; j < DD; ++j) acc += dWih[(size_t)tid * HH + j] * oB[j];
    decB2[tid] = acc;
  }
}

// W2 = dec_Whh + dec_Wih[:,:D] @ out_W   (4096 x 1024)
__global__ void k_prep_decw2(const float* __restrict__ dWih, const float* __restrict__ dWhh,
                             const float* __restrict__ oW, _Float16* __restrict__ decW2) {
  int r = blockIdx.x >> 2;                       // 0..4095
  int c = ((blockIdx.x & 3) << 8) + threadIdx.x; // 0..1023
  float acc = dWhh[(size_t)r * HH + c];
  for (int j = 0; j < DD; ++j) acc += dWih[(size_t)r * HH + j] * oW[(size_t)j * HH + c];
  decW2[(size_t)r * HH + c] = (_Float16)acc;
}

// ---- barrier ----------------------------------------------------------------
// Arrival: after per-wave vmcnt(0) drain (write-through h stores acked at the
// coherence point) + __syncthreads, thread 0 publishes its generation to the
// block's own slot (relaxed atomic STORE — zero RMW serialization).
__device__ __forceinline__ void bar_arrive(unsigned* slot, unsigned step) {
  asm volatile("s_waitcnt vmcnt(0)" ::: "memory");
  __syncthreads();
  if (threadIdx.x == 0)
    __hip_atomic_store(slot, step, __ATOMIC_RELAXED, __HIP_MEMORY_SCOPE_AGENT);
}
// Wait: the LAST polln threads (waves with no x-work) each poll one slot with
// relaxed atomic loads (memory-side, no cache maintenance), then block syncs.
__device__ __forceinline__ void bar_wait(unsigned* slots, int polln, unsigned step) {
  int pi = (int)threadIdx.x - (512 - polln);
  if (pi >= 0) {
    unsigned* p = slots + (size_t)pi * SLOTSTRIDE;
    while (__hip_atomic_load(p, __ATOMIC_RELAXED, __HIP_MEMORY_SCOPE_AGENT) < step)
      __builtin_amdgcn_s_sleep(4);
  }
  __syncthreads();
}

// ---- persistent sequence kernel --------------------------------------------
// Grid 256 = (mtb 0..3)<<6 | (ut 0..63); 512 threads = 8 waves (K-split).
// Block (mtb,ut) reads h rows [mtb*32, mtb*32+32) — produced only by the 64
// blocks sharing mtb -> per-mtb group barriers (4 independent, 64 slots each).

__global__ __launch_bounds__(512, 2) void k_seq(
    const float* __restrict__ x, const _Float16* __restrict__ x16,
    const _Float16* __restrict__ encW, const float* __restrict__ encB,
    const _Float16* __restrict__ decW1, const _Float16* __restrict__ decW2,
    const float* __restrict__ decB1, const float* __restrict__ decB2,
    const _Float16* __restrict__ outW, const float* __restrict__ oB,
    _Float16* __restrict__ hA, _Float16* __restrict__ hB,
    float* __restrict__ encOut, float* __restrict__ recon,
    float* __restrict__ lossAcc, float* __restrict__ lossOut,
    unsigned* __restrict__ bar) {
  __shared__ float pl[4][4][2][16][RP];   // 40 KB
  __shared__ float red[4][2][16][RP];     // 10 KB
  __shared__ float pY[4][2][16][RP];      // 10 KB
  __shared__ float redY[2][16][RP];       // 2.5 KB

  const int tid = threadIdx.x;
  const int lane = tid & 63, w = tid >> 6;
  const int n = lane & 15, q = lane >> 4;
  const int ut = (int)blockIdx.x & 63, mtb = (int)blockIdx.x >> 6;
  const int m0 = mtb << 5, u0 = ut << 4;
  const int kh0 = w << 7;

  const int m_l = tid >> 4, u_l = tid & 15;
  const int mtc = m_l >> 4, rowc = m_l & 15;
  const int cm = m0 + m_l, cu = u0 + u_l;
  const size_t hidx = (size_t)cm * HH + cu;

  unsigned* myslot = bar + (size_t)blockIdx.x * SLOTSTRIDE;
  unsigned* grpSlots = bar + (size_t)(mtb * 64) * SLOTSTRIDE;
  float creg = 0.0f;

  // -------- encoder weights -> registers (loop-invariant) --------
  half8 bw[4][4];
  half8 xw[4];
  {
    const _Float16* base = encW + (size_t)(u0 + n) * KENC + (size_t)(DD + kh0 + q * 8);
#pragma unroll
    for (int g = 0; g < 4; ++g)
#pragma unroll
      for (int kk = 0; kk < 4; ++kk)
        bw[g][kk] = *(const half8*)(base + (size_t)g * ((size_t)HH * KENC) + kk * 32);
    if (w < 4) {
      const _Float16* xb = encW + (size_t)(u0 + n) * KENC + (size_t)((w << 5) + q * 8);
#pragma unroll
      for (int g = 0; g < 4; ++g)
        xw[g] = *(const half8*)(xb + (size_t)g * ((size_t)HH * KENC));
    }
  }
  float b0 = encB[cu], b1 = encB[HH + cu], b2 = encB[2 * HH + cu], b3 = encB[3 * HH + cu];

  const _Float16* hrowA = hA + (size_t)(m0 + n) * HH + kh0 + q * 8;
  const _Float16* hrowB = hB + (size_t)(m0 + n) * HH + kh0 + q * 8;
  const _Float16* x16r0 = x16 + (size_t)(m0 + n) * ((size_t)SS * DD) + (size_t)((w << 5) + q * 8);
  const _Float16* x16r1 = x16r0 + (size_t)16 * ((size_t)SS * DD);
  float* encPtr = encOut + (size_t)cm * ((size_t)SS * HH) + cu;

  // ================= encoder =================
  for (int t = 0; t < SS; ++t) {
    floatx4 acc[4][2];
#pragma unroll
    for (int g = 0; g < 4; ++g) {
      acc[g][0] = (floatx4){0, 0, 0, 0};
      acc[g][1] = (floatx4){0, 0, 0, 0};
    }
    if (w < 4) {  // x part — independent of h(t); overlaps the barrier wait
      half8 xa0 = *(const half8*)(x16r0 + (size_t)t * DD);
      half8 xa1 = *(const half8*)(x16r1 + (size_t)t * DD);
      acc[0][0] = MFMA16(xa0, xw[0], acc[0][0]); acc[0][1] = MFMA16(xa1, xw[0], acc[0][1]);
      acc[1][0] = MFMA16(xa0, xw[1], acc[1][0]); acc[1][1] = MFMA16(xa1, xw[1], acc[1][1]);
      acc[2][0] = MFMA16(xa0, xw[2], acc[2][0]); acc[2][1] = MFMA16(xa1, xw[2], acc[2][1]);
      acc[3][0] = MFMA16(xa0, xw[3], acc[3][0]); acc[3][1] = MFMA16(xa1, xw[3], acc[3][1]);
    }
    if (t > 0) bar_wait(grpSlots, 64, (unsigned)t);

    const _Float16* h0 = (t & 1) ? hrowB : hrowA;
    const _Float16* h1 = h0 + (size_t)16 * HH;
    half8 ha[4], hb[4];
#pragma unroll
    for (int kk = 0; kk < 4; ++kk) {
      ha[kk] = ldg_h8_sc(h0 + kk * 32);
      hb[kk] = ldg_h8_sc(h1 + kk * 32);
    }
    asm volatile("s_waitcnt vmcnt(0)" ::: "memory");
    __builtin_amdgcn_sched_barrier(0);
#pragma unroll
    for (int kk = 0; kk < 4; ++kk) {
      acc[0][0] = MFMA16(ha[kk], bw[0][kk], acc[0][0]); acc[0][1] = MFMA16(hb[kk], bw[0][kk], acc[0][1]);
      acc[1][0] = MFMA16(ha[kk], bw[1][kk], acc[1][0]); acc[1][1] = MFMA16(hb[kk], bw[1][kk], acc[1][1]);
      acc[2][0] = MFMA16(ha[kk], bw[2][kk], acc[2][0]); acc[2][1] = MFMA16(hb[kk], bw[2][kk], acc[2][1]);
      acc[3][0] = MFMA16(ha[kk], bw[3][kk], acc[3][0]); acc[3][1] = MFMA16(hb[kk], bw[3][kk], acc[3][1]);
    }

    // 2-level reduction tree over the 8 K-slices
    if (w >= 4) {
#pragma unroll
      for (int g = 0; g < 4; ++g)
#pragma unroll
        for (int mt = 0; mt < 2; ++mt)
#pragma unroll
          for (int r = 0; r < 4; ++r)
            pl[w - 4][g][mt][q * 4 + r][n] = acc[g][mt][r];
    }
    __syncthreads();
    if (w < 4) {
#pragma unroll
      for (int g = 0; g < 4; ++g)
#pragma unroll
        for (int mt = 0; mt < 2; ++mt)
#pragma unroll
          for (int r = 0; r < 4; ++r) {
            acc[g][mt][r] += pl[w][g][mt][q * 4 + r][n];
            pl[w][g][mt][q * 4 + r][n] = acc[g][mt][r];
          }
    }
    __syncthreads();
    {
      int base = tid * 4;
      int col = base & 15, row = (base >> 4) & 15, mt = (base >> 8) & 1, g = base >> 9;
      floatx4 s = *(const floatx4*)&pl[0][g][mt][row][col];
      s += *(const floatx4*)&pl[1][g][mt][row][col];
      s += *(const floatx4*)&pl[2][g][mt][row][col];
      s += *(const floatx4*)&pl[3][g][mt][row][col];
      *(floatx4*)&red[g][mt][row][col] = s;
    }
    __syncthreads();
    {
      float gi = sigf(red[0][mtc][rowc][u_l] + b0);
      float gf = sigf(red[1][mtc][rowc][u_l] + b1);
      float gg = tanhfast(red[2][mtc][rowc][u_l] + b2);
      float go = sigf(red[3][mtc][rowc][u_l] + b3);
      float cv = gf * creg + gi * gg;
      creg = cv;
      float hv = go * tanhfast(cv);
      stg_h_sc(((t & 1) ? hA : hB) + hidx, (_Float16)hv);
      encPtr[0] = hv;
      encPtr += HH;
    }
    bar_arrive(myslot, (unsigned)(t + 1));
  }

  // ================= decoder =================
  {
    const _Float16* base = decW1 + (size_t)(u0 + n) * HH + (size_t)(kh0 + q * 8);
#pragma unroll
    for (int g = 0; g < 4; ++g)
#pragma unroll
      for (int kk = 0; kk < 4; ++kk)
        bw[g][kk] = *(const half8*)(base + (size_t)g * ((size_t)HH * HH) + kk * 32);
  }
  b0 = decB1[cu]; b1 = decB1[HH + cu]; b2 = decB1[2 * HH + cu]; b3 = decB1[3 * HH + cu];

  half8 ow[4];
  if (ut < 8) {
    const _Float16* oro = outW + (size_t)(u0 + n) * HH + (size_t)(kh0 + q * 8);
#pragma unroll
    for (int kk = 0; kk < 4; ++kk) ow[kk] = *(const half8*)(oro + kk * 32);
  }
  const float obv_cu = (ut < 8) ? oB[cu] : 0.0f;

  for (int s = 1; s <= SS; ++s) {
    if (s == 2) {  // switch to W2 = dec_Whh + dec_Wih[:,:D]@out_W (before wait: overlaps)
      const _Float16* base = decW2 + (size_t)(u0 + n) * HH + (size_t)(kh0 + q * 8);
#pragma unroll
      for (int g = 0; g < 4; ++g)
#pragma unroll
        for (int kk = 0; kk < 4; ++kk)
          bw[g][kk] = *(const half8*)(base + (size_t)g * ((size_t)HH * HH) + kk * 32);
      b0 = decB2[cu]; b1 = decB2[HH + cu]; b2 = decB2[2 * HH + cu]; b3 = decB2[3 * HH + cu];
    }
    bar_wait(grpSlots, 64, (unsigned)(511 + s));

    const int p = 511 + s;
    const _Float16* h0 = (p & 1) ? hrowB : hrowA;
    const _Float16* h1 = h0 + (size_t)16 * HH;
    const bool doY = (s >= 2) && (ut < 8);

    floatx4 acc[4][2];
#pragma unroll
    for (int g = 0; g < 4; ++g) {
      acc[g][0] = (floatx4){0, 0, 0, 0};
      acc[g][1] = (floatx4){0, 0, 0, 0};
    }
    floatx4 accY[2];
    accY[0] = (floatx4){0, 0, 0, 0}; accY[1] = (floatx4){0, 0, 0, 0};

    half8 ha[4], hb[4];
#pragma unroll
    for (int kk = 0; kk < 4; ++kk) {
      ha[kk] = ldg_h8_sc(h0 + kk * 32);
      hb[kk] = ldg_h8_sc(h1 + kk * 32);
    }
    asm volatile("s_waitcnt vmcnt(0)" ::: "memory");
    __builtin_amdgcn_sched_barrier(0);
#pragma unroll
    for (int kk = 0; kk < 4; ++kk) {
      acc[0][0] = MFMA16(ha[kk], bw[0][kk], acc[0][0]); acc[0][1] = MFMA16(hb[kk], bw[0][kk], acc[0][1]);
      acc[1][0] = MFMA16(ha[kk], bw[1][kk], acc[1][0]); acc[1][1] = MFMA16(hb[kk], bw[1][kk], acc[1][1]);
      acc[2][0] = MFMA16(ha[kk], bw[2][kk], acc[2][0]); acc[2][1] = MFMA16(hb[kk], bw[2][kk], acc[2][1]);
      acc[3][0] = MFMA16(ha[kk], bw[3][kk], acc[3][0]); acc[3][1] = MFMA16(hb[kk], bw[3][kk], acc[3][1]);
      if (doY) {
        accY[0] = MFMA16(ha[kk], ow[kk], accY[0]);
        accY[1] = MFMA16(hb[kk], ow[kk], accY[1]);
      }
    }

    if (w >= 4) {
#pragma unroll
      for (int g = 0; g < 4; ++g)
#pragma unroll
        for (int mt = 0; mt < 2; ++mt)
#pragma unroll
          for (int r = 0; r < 4; ++r)
            pl[w - 4][g][mt][q * 4 + r][n] = acc[g][mt][r];
      if (doY)
#pragma unroll
        for (int mt = 0; mt < 2; ++mt)
#pragma unroll
          for (int r = 0; r < 4; ++r)
            pY[w - 4][mt][q * 4 + r][n] = accY[mt][r];
    }
    __syncthreads();
    if (w < 4) {
#pragma unroll
      for (int g = 0; g < 4; ++g)
#pragma unroll
        for (int mt = 0; mt < 2; ++mt)
#pragma unroll
          for (int r = 0; r < 4; ++r) {
            acc[g][mt][r] += pl[w][g][mt][q * 4 + r][n];
            pl[w][g][mt][q * 4 + r][n] = acc[g][mt][r];
          }
      if (doY)
#pragma unroll
        for (int mt = 0; mt < 2; ++mt)
#pragma unroll
          for (int r = 0; r < 4; ++r) {
            accY[mt][r] += pY[w][mt][q * 4 + r][n];
            pY[w][mt][q * 4 + r][n] = accY[mt][r];
          }
    }
    __syncthreads();
    {
      int base = tid * 4;
      int col = base & 15, row = (base >> 4) & 15, mt = (base >> 8) & 1, g = base >> 9;
      floatx4 sv = *(const floatx4*)&pl[0][g][mt][row][col];
      sv += *(const floatx4*)&pl[1][g][mt][row][col];
      sv += *(const floatx4*)&pl[2][g][mt][row][col];
      sv += *(const floatx4*)&pl[3][g][mt][row][col];
      *(floatx4*)&red[g][mt][row][col] = sv;
    }
    if (doY && tid < 128) {
      int base = tid * 4;
      int col = base & 15, row = (base >> 4) & 15, mt = (base >> 8) & 1;
      floatx4 sv = *(const floatx4*)&pY[0][mt][row][col];
      sv += *(const floatx4*)&pY[1][mt][row][col];
      sv += *(const floatx4*)&pY[2][mt][row][col];
      sv += *(const floatx4*)&pY[3][mt][row][col];
      *(floatx4*)&redY[mt][row][col] = sv;
    }
    __syncthreads();
    {
      float gi = sigf(red[0][mtc][rowc][u_l] + b0);
      float gf = sigf(red[1][mtc][rowc][u_l] + b1);
      float gg = tanhfast(red[2][mtc][rowc][u_l] + b2);
      float go = sigf(red[3][mtc][rowc][u_l] + b3);
      float cv = gf * creg + gi * gg;
      creg = cv;
      float hv = go * tanhfast(cv);
      stg_h_sc(((p & 1) ? hA : hB) + hidx, (_Float16)hv);
      if (doY) {
        int ty = s - 2;
        float yv = redY[mtc][rowc][u_l] + obv_cu;
        size_t ix = (size_t)cm * ((size_t)SS * DD) + (size_t)ty * DD + cu;
        recon[ix] = yv;
        float e = yv - x[ix];
        float ls = e * e;
#pragma unroll
        for (int off = 32; off; off >>= 1) ls += __shfl_xor(ls, off, 64);
        if (lane == 0) atomicAdd(lossAcc, ls);
      }
    }
    bar_arrive(myslot, (unsigned)(512 + s));
  }

  // ---- final y (recon[:,511]) from final h (p=1023 wrote hA) ----
  bar_wait(bar, 256, 1024u);   // global: final-Y blocks read rows of all groups
  if ((int)blockIdx.x < 64 && tid < 64) {
    const int fmt = (int)blockIdx.x >> 3, fdt = (int)blockIdx.x & 7;
    const int fm0 = fmt << 4, d0 = fdt << 4;
    floatx4 a4 = (floatx4){0, 0, 0, 0};
    const _Float16* hrow = hA + (size_t)(fm0 + n) * HH + q * 8;
    const _Float16* orow = outW + (size_t)(d0 + n) * HH + q * 8;
    for (int kb = 0; kb < 32; kb += 8) {
      half8 hh[8];
#pragma unroll
      for (int j = 0; j < 8; ++j) hh[j] = ldg_h8_sc(hrow + (size_t)(kb + j) * 32);
      asm volatile("s_waitcnt vmcnt(0)" ::: "memory");
      __builtin_amdgcn_sched_barrier(0);
#pragma unroll
      for (int j = 0; j < 8; ++j)
        a4 = MFMA16(hh[j], *(const half8*)(orow + (size_t)(kb + j) * 32), a4);
    }
    int d = d0 + n;
    float ob2 = oB[d];
    float ls = 0.0f;
#pragma unroll
    for (int r = 0; r < 4; ++r) {
      int m = fm0 + q * 4 + r;
      float yv = a4[r] + ob2;
      size_t ix = (size_t)m * ((size_t)SS * DD) + (size_t)(SS - 1) * DD + d;
      recon[ix] = yv;
      float e = yv - x[ix];
      ls += e * e;
    }
#pragma unroll
    for (int off = 32; off; off >>= 1) ls += __shfl_xor(ls, off, 64);
    if (lane == 0) atomicAdd(lossAcc, ls);
  }
  bar_arrive(myslot, 1025u);
  bar_wait(bar, 256, 1025u);
  if (blockIdx.x == 0 && tid == 0)
    lossOut[0] = __hip_atomic_load(lossAcc, __ATOMIC_RELAXED, __HIP_MEMORY_SCOPE_AGENT) *
                 (1.0f / (float)BB);
}

// ---- host -------------------------------------------------------------------

extern "C" void kernel_launch(void* const* d_in, const int* in_sizes, int n_in,
                              void* d_out, int out_size, void* d_ws, size_t ws_size,
                              hipStream_t stream) {
  const float* x    = (const float*)d_in[0];
  const float* eWih = (const float*)d_in[1];
  const float* eWhh = (const float*)d_in[2];
  const float* eBih = (const float*)d_in[3];
  const float* eBhh = (const float*)d_in[4];
  const float* dWih = (const float*)d_in[5];
  const float* dWhh = (const float*)d_in[6];
  const float* dBih = (const float*)d_in[7];
  const float* dBhh = (const float*)d_in[8];
  const float* oW   = (const float*)d_in[9];
  const float* oB   = (const float*)d_in[10];

  float* out = (float*)d_out;
  float* recon = out;                                   // (B,S,D)
  float* encOut = out + (size_t)BB * SS * DD;           // (B,S,H)
  float* lossOut = out + (size_t)BB * SS * DD + (size_t)BB * SS * HH;  // scalar

  char* p = (char*)d_ws;
  auto alloc = [&](size_t bytes) {
    char* r = p;
    p += (bytes + 255) & ~(size_t)255;
    return r;
  };
  _Float16* encW   = (_Float16*)alloc((size_t)G4 * KENC * 2);  // [Wih|Whh] fp16
  _Float16* decW1  = (_Float16*)alloc((size_t)G4 * HH * 2);
  _Float16* decW2  = (_Float16*)alloc((size_t)G4 * HH * 2);
  _Float16* outW16 = (_Float16*)alloc((size_t)DD * HH * 2);
  _Float16* x16    = (_Float16*)alloc((size_t)BB * SS * DD * 2);
  float* encB  = (float*)alloc((size_t)G4 * 4);
  float* decB1 = (float*)alloc((size_t)G4 * 4);
  float* decB2 = (float*)alloc((size_t)G4 * 4);
  _Float16* hA = (_Float16*)alloc((size_t)BB * HH * 2);
  _Float16* hB = (_Float16*)alloc((size_t)BB * HH * 2);
  float* lossAcc = (float*)alloc(256);
  unsigned* bar = (unsigned*)alloc((size_t)NBLK * SLOTSTRIDE * 4);
  (void)in_sizes; (void)n_in; (void)out_size; (void)ws_size;

  k_prep_encw<<<G4, 256, 0, stream>>>(eWih, eWhh, encW);
  k_prep_simple<<<2048, 256, 0, stream>>>(x, dWih, dWhh, oW, eBih, eBhh, dBih, dBhh, oB,
                                          x16, decW1, outW16, encB, decB1, decB2, hA,
                                          lossAcc, bar);
  k_prep_decw2<<<G4 * 4, 256, 0, stream>>>(dWih, dWhh, oW, decW2);

  void* args[] = {(void*)&x, (void*)&x16, (void*)&encW, (void*)&encB, (void*)&decW1,
                  (void*)&decW2, (void*)&decB1, (void*)&decB2, (void*)&outW16, (void*)&oB,
                  (void*)&hA, (void*)&hB, (void*)&encOut, (void*)&recon,
                  (void*)&lossAcc, (void*)&lossOut, (void*)&bar};
  (void)hipLaunchCooperativeKernel((void*)k_seq, dim3(NBLK), dim3(512), args, 0, stream);
}

// Round 5
// 5703.875 us; speedup vs baseline: 6.1999x; 1.0760x over previous
//
#include <hip/hip_runtime.h>

// LSTM autoencoder, MI355X. Round 6b: persistent cooperative kernel.
// (Round 6a failed to compile: braced init list inside MFMA16 macro arg.)
// Round-5 post-mortem: 5.6us/step; remaining cost = (a) 256 same-line loss
// atomicAdds per dec step inside the pre-arrival drain, (b) 2-level LDS tree
// (3 syncs, gather conflicts: SQ_LDS_BANK_CONFLICT pinned at 1.02e8),
// (c) full-group (64-slot) waits. Fixes:
//  * loss accumulated in a register, ONE atomicAdd per block at kernel end.
//  * wave remap: wave = (mtile, K-slice-256). Full-K MFMA chains per gate in
//    registers (bw[4][8] = 128 VGPR), partials written ONCE, single sync,
//    scalar 4-way gather (2-way bank aliasing = free).
//  * wave-autonomous wait: each wave polls only its 16 producer blocks
//    (lanes 0..15), no wait-side block sync. Arrive stays block-wide (drain +
//    sync + slot store). Double-buffer WAR safe: h_{k+1} store is after the
//    block sync that joins all 8 waves' waits (covering all 64 producers >= k).

#define BB 128
#define SS 512
#define DD 128
#define HH 1024
#define G4 4096
#define KENC 1152
#define NBLK 256
#define RP 20          // padded row width (floats) for LDS partial tiles
#define SLOTSTRIDE 16  // u32s per barrier slot (64B)

typedef _Float16 half8 __attribute__((ext_vector_type(8)));
typedef float floatx4 __attribute__((ext_vector_type(4)));

__device__ __forceinline__ float sigf(float x) { return 1.0f / (1.0f + __expf(-x)); }
__device__ __forceinline__ float tanhfast(float x) { return 1.0f - 2.0f / (1.0f + __expf(2.0f * x)); }

#define MFMA16(a, b, c) __builtin_amdgcn_mfma_f32_16x16x32_f16((a), (b), (c), 0, 0, 0)

// L2-bypass (coherence-point) 16B load.
__device__ __forceinline__ half8 ldg_h8_sc(const _Float16* p) {
  floatx4 t;
  asm volatile("global_load_dwordx4 %0, %1, off sc0 sc1" : "=v"(t) : "v"(p) : "memory");
  return __builtin_bit_cast(half8, t);
}
// Write-through 2B store: visible at coherence point once vmcnt retires.
__device__ __forceinline__ void stg_h_sc(_Float16* p, _Float16 v) {
  unsigned u = (unsigned)__builtin_bit_cast(unsigned short, v);
  asm volatile("global_store_short %0, %1, off sc0 sc1" :: "v"(p), "v"(u) : "memory");
}

// ---- prep kernels -----------------------------------------------------------

__global__ void k_prep_encw(const float* __restrict__ eWih, const float* __restrict__ eWhh,
                            _Float16* __restrict__ encW) {
  int r = blockIdx.x;  // 0..4095
  for (int k = threadIdx.x; k < KENC; k += blockDim.x) {
    float v = (k < DD) ? eWih[(size_t)r * DD + k] : eWhh[(size_t)r * HH + (k - DD)];
    encW[(size_t)r * KENC + k] = (_Float16)v;
  }
}

__global__ void k_prep_simple(const float* __restrict__ x, const float* __restrict__ dWih,
                              const float* __restrict__ dWhh, const float* __restrict__ oW,
                              const float* __restrict__ eBih, const float* __restrict__ eBhh,
                              const float* __restrict__ dBih, const float* __restrict__ dBhh,
                              const float* __restrict__ oB,
                              _Float16* __restrict__ x16,
                              _Float16* __restrict__ decW1, _Float16* __restrict__ outW16,
                              float* __restrict__ encB, float* __restrict__ decB1,
                              float* __restrict__ decB2,
                              _Float16* __restrict__ hA, float* __restrict__ lossAcc,
                              unsigned* __restrict__ bar) {
  int tid = blockIdx.x * blockDim.x + threadIdx.x;
  int nt = gridDim.x * blockDim.x;
  for (size_t i = tid; i < (size_t)G4 * HH; i += nt)
    decW1[i] = (_Float16)(dWih[i] + dWhh[i]);   // dec step1: inp==h_n -> Wih+Whh
  for (size_t i = tid; i < (size_t)BB * SS * DD; i += nt)
    x16[i] = (_Float16)x[i];
  for (size_t i = tid; i < (size_t)DD * HH; i += nt)
    outW16[i] = (_Float16)oW[i];
  for (size_t i = tid; i < (size_t)BB * HH; i += nt)
    hA[i] = (_Float16)0.0f;
  for (size_t i = tid; i < (size_t)NBLK * SLOTSTRIDE; i += nt)
    bar[i] = 0u;
  if (tid == 0) lossAcc[0] = 0.0f;
  if (tid < G4) {
    encB[tid] = eBih[tid] + eBhh[tid];
    float b1 = dBih[tid] + dBhh[tid];
    decB1[tid] = b1;
    float acc = b1;  // b2 = b1 + dec_Wih[:,:D] @ out_b
    for (int j = 0; j < DD; ++j) acc += dWih[(size_t)tid * HH + j] * oB[j];
    decB2[tid] = acc;
  }
}

// W2 = dec_Whh + dec_Wih[:,:D] @ out_W   (4096 x 1024)
__global__ void k_prep_decw2(const float* __restrict__ dWih, const float* __restrict__ dWhh,
                             const float* __restrict__ oW, _Float16* __restrict__ decW2) {
  int r = blockIdx.x >> 2;                       // 0..4095
  int c = ((blockIdx.x & 3) << 8) + threadIdx.x; // 0..1023
  float acc = dWhh[(size_t)r * HH + c];
  for (int j = 0; j < DD; ++j) acc += dWih[(size_t)r * HH + j] * oW[(size_t)j * HH + c];
  decW2[(size_t)r * HH + c] = (_Float16)acc;
}

// ---- barrier primitives -----------------------------------------------------

__device__ __forceinline__ void block_arrive(unsigned* slot, unsigned step) {
  asm volatile("s_waitcnt vmcnt(0)" ::: "memory");  // h write-through stores acked
  __syncthreads();
  if (threadIdx.x == 0)
    __hip_atomic_store(slot, step, __ATOMIC_RELAXED, __HIP_MEMORY_SCOPE_AGENT);
}
// Wave polls its 16 producer blocks' slots (lanes 0..15); no block sync.
__device__ __forceinline__ void wave_wait16(unsigned* slots, unsigned step) {
  int l = (int)threadIdx.x & 63;
  if (l < 16) {
    unsigned* p = slots + (size_t)l * SLOTSTRIDE;
    while (__hip_atomic_load(p, __ATOMIC_RELAXED, __HIP_MEMORY_SCOPE_AGENT) < step)
      __builtin_amdgcn_s_sleep(2);
  }
}
__device__ __forceinline__ void bar_wait_all(unsigned* bar, unsigned step) {
  int pi = (int)threadIdx.x;
  if (pi < NBLK) {
    unsigned* p = bar + (size_t)pi * SLOTSTRIDE;
    while (__hip_atomic_load(p, __ATOMIC_RELAXED, __HIP_MEMORY_SCOPE_AGENT) < step)
      __builtin_amdgcn_s_sleep(2);
  }
  __syncthreads();
}

// ---- persistent sequence kernel --------------------------------------------
// Grid 256 = (mtb 0..3)<<6 | (ut 0..63); 512 threads = 8 waves.
// Wave w: mtw = w>>2 (16-row mtile), ksl = w&3 (256-wide K slice).
// Per wave: 4 gate chains x (8 h-MFMAs [+1 x-MFMA enc]); partials -> LDS once.
// MFMA 16x16x32_f16: A[m=lane&15][k=(lane>>4)*8+j], C: row=(lane>>4)*4+r, col=lane&15.

__global__ __launch_bounds__(512, 2) void k_seq(
    const float* __restrict__ x, const _Float16* __restrict__ x16,
    const _Float16* __restrict__ encW, const float* __restrict__ encB,
    const _Float16* __restrict__ decW1, const _Float16* __restrict__ decW2,
    const float* __restrict__ decB1, const float* __restrict__ decB2,
    const _Float16* __restrict__ outW, const float* __restrict__ oB,
    _Float16* __restrict__ hA, _Float16* __restrict__ hB,
    float* __restrict__ encOut, float* __restrict__ recon,
    float* __restrict__ lossAcc, float* __restrict__ lossOut,
    unsigned* __restrict__ bar) {
  __shared__ float pl[4][4][2][16][RP];   // [ksl][gate][mt][row][col] 40 KB
  __shared__ float pY[4][2][16][RP];      // 10 KB
  __shared__ float lred[8];

  const int tid = threadIdx.x;
  const int lane = tid & 63, w = tid >> 6;
  const int n = lane & 15, q = lane >> 4;
  const int mtw = w >> 2, ksl = w & 3;
  const int ut = (int)blockIdx.x & 63, mtb = (int)blockIdx.x >> 6;
  const int m0 = mtb << 5, u0 = ut << 4;

  const int m_l = tid >> 4, u_l = tid & 15;
  const int mtc = m_l >> 4, rowc = m_l & 15;
  const int cm = m0 + m_l, cu = u0 + u_l;
  const size_t hidx = (size_t)cm * HH + cu;

  const floatx4 zero4 = {0.0f, 0.0f, 0.0f, 0.0f};

  unsigned* myslot = bar + (size_t)blockIdx.x * SLOTSTRIDE;
  // this wave's 16 producer blocks: ut' in [ksl*16, ksl*16+16) of same mtb
  unsigned* prodSlots = bar + (size_t)(mtb * 64 + ksl * 16) * SLOTSTRIDE;
  float creg = 0.0f;
  float lossReg = 0.0f;

  // -------- encoder weights -> registers (loop-invariant) --------
  half8 bw[4][8];   // [gate][kk]: rows u0+n, cols ksl*256 + kk*32 + q*8 (h part)
  half8 xw[4];      // x part: cols ksl*32 + q*8
  {
    const _Float16* base = encW + (size_t)(u0 + n) * KENC + (size_t)(DD + ksl * 256 + q * 8);
    const _Float16* xb   = encW + (size_t)(u0 + n) * KENC + (size_t)(ksl * 32 + q * 8);
#pragma unroll
    for (int g = 0; g < 4; ++g) {
#pragma unroll
      for (int kk = 0; kk < 8; ++kk)
        bw[g][kk] = *(const half8*)(base + (size_t)g * ((size_t)HH * KENC) + kk * 32);
      xw[g] = *(const half8*)(xb + (size_t)g * ((size_t)HH * KENC));
    }
  }
  float b0 = encB[cu], b1 = encB[HH + cu], b2 = encB[2 * HH + cu], b3 = encB[3 * HH + cu];

  // step-invariant pointers (wave's 16 rows x 256-col K slice)
  const _Float16* hTA = hA + (size_t)(m0 + mtw * 16 + n) * HH + ksl * 256 + q * 8;
  const _Float16* hTB = hB + (size_t)(m0 + mtw * 16 + n) * HH + ksl * 256 + q * 8;
  const _Float16* xp = x16 + (size_t)(m0 + mtw * 16 + n) * ((size_t)SS * DD) + ksl * 32 + q * 8;
  float* encPtr = encOut + (size_t)cm * ((size_t)SS * HH) + cu;

  // ================= encoder =================
  for (int t = 0; t < SS; ++t) {
    half8 xa = *(const half8*)(xp + (size_t)t * DD);   // independent of h: before wait
    if (t > 0) wave_wait16(prodSlots, (unsigned)t);

    const _Float16* hsrc = (t & 1) ? hTB : hTA;
    half8 ha[8];
#pragma unroll
    for (int kk = 0; kk < 8; ++kk) ha[kk] = ldg_h8_sc(hsrc + kk * 32);
    asm volatile("s_waitcnt vmcnt(0)" ::: "memory");
    __builtin_amdgcn_sched_barrier(0);

    floatx4 acc[4];
#pragma unroll
    for (int g = 0; g < 4; ++g) acc[g] = MFMA16(xa, xw[g], zero4);
#pragma unroll
    for (int kk = 0; kk < 8; ++kk)
#pragma unroll
      for (int g = 0; g < 4; ++g)
        acc[g] = MFMA16(ha[kk], bw[g][kk], acc[g]);

#pragma unroll
    for (int g = 0; g < 4; ++g)
#pragma unroll
      for (int r = 0; r < 4; ++r)
        pl[ksl][g][mtw][q * 4 + r][n] = acc[g][r];
    __syncthreads();

    {  // update: thread (m_l, u_l); gather 4 K-slice partials per gate
      float s0 = pl[0][0][mtc][rowc][u_l] + pl[1][0][mtc][rowc][u_l] +
                 pl[2][0][mtc][rowc][u_l] + pl[3][0][mtc][rowc][u_l];
      float s1 = pl[0][1][mtc][rowc][u_l] + pl[1][1][mtc][rowc][u_l] +
                 pl[2][1][mtc][rowc][u_l] + pl[3][1][mtc][rowc][u_l];
      float s2 = pl[0][2][mtc][rowc][u_l] + pl[1][2][mtc][rowc][u_l] +
                 pl[2][2][mtc][rowc][u_l] + pl[3][2][mtc][rowc][u_l];
      float s3 = pl[0][3][mtc][rowc][u_l] + pl[1][3][mtc][rowc][u_l] +
                 pl[2][3][mtc][rowc][u_l] + pl[3][3][mtc][rowc][u_l];
      float gi = sigf(s0 + b0);
      float gf = sigf(s1 + b1);
      float gg = tanhfast(s2 + b2);
      float go = sigf(s3 + b3);
      float cv = gf * creg + gi * gg;
      creg = cv;
      float hv = go * tanhfast(cv);
      stg_h_sc(((t & 1) ? hA : hB) + hidx, (_Float16)hv);
      encPtr[0] = hv;
      encPtr += HH;
    }
    block_arrive(myslot, (unsigned)(t + 1));
  }

  // ================= decoder =================
  {  // step-1 weights (inp == h_n -> Wih+Whh, precomputed)
    const _Float16* base = decW1 + (size_t)(u0 + n) * HH + (size_t)(ksl * 256 + q * 8);
#pragma unroll
    for (int g = 0; g < 4; ++g)
#pragma unroll
      for (int kk = 0; kk < 8; ++kk)
        bw[g][kk] = *(const half8*)(base + (size_t)g * ((size_t)HH * HH) + kk * 32);
  }
  b0 = decB1[cu]; b1 = decB1[HH + cu]; b2 = decB1[2 * HH + cu]; b3 = decB1[3 * HH + cu];

  const bool isY = (ut < 8);
  const _Float16* owp = outW + (size_t)(u0 + n) * HH + ksl * 256 + q * 8;
  const float obv_cu = isY ? oB[cu] : 0.0f;

  for (int s = 1; s <= SS; ++s) {
    if (s == 2) {  // switch to W2 = dec_Whh + dec_Wih[:,:D]@out_W (before wait)
      const _Float16* base = decW2 + (size_t)(u0 + n) * HH + (size_t)(ksl * 256 + q * 8);
#pragma unroll
      for (int g = 0; g < 4; ++g)
#pragma unroll
        for (int kk = 0; kk < 8; ++kk)
          bw[g][kk] = *(const half8*)(base + (size_t)g * ((size_t)HH * HH) + kk * 32);
      b0 = decB2[cu]; b1 = decB2[HH + cu]; b2 = decB2[2 * HH + cu]; b3 = decB2[3 * HH + cu];
    }
    const int p = 511 + s;
    const bool doY = (s >= 2) && isY;

    wave_wait16(prodSlots, (unsigned)p);

    const _Float16* hsrc = (p & 1) ? hTB : hTA;
    half8 ha[8];
#pragma unroll
    for (int kk = 0; kk < 8; ++kk) ha[kk] = ldg_h8_sc(hsrc + kk * 32);
    asm volatile("s_waitcnt vmcnt(0)" ::: "memory");
    __builtin_amdgcn_sched_barrier(0);

    floatx4 acc[4];
#pragma unroll
    for (int g = 0; g < 4; ++g) acc[g] = zero4;
    floatx4 accY = zero4;
#pragma unroll
    for (int kk = 0; kk < 8; ++kk) {
#pragma unroll
      for (int g = 0; g < 4; ++g)
        acc[g] = MFMA16(ha[kk], bw[g][kk], acc[g]);
      if (doY) accY = MFMA16(ha[kk], *(const half8*)(owp + kk * 32), accY);
    }

#pragma unroll
    for (int g = 0; g < 4; ++g)
#pragma unroll
      for (int r = 0; r < 4; ++r)
        pl[ksl][g][mtw][q * 4 + r][n] = acc[g][r];
    if (doY)
#pragma unroll
      for (int r = 0; r < 4; ++r)
        pY[ksl][mtw][q * 4 + r][n] = accY[r];
    __syncthreads();

    {
      float s0 = pl[0][0][mtc][rowc][u_l] + pl[1][0][mtc][rowc][u_l] +
                 pl[2][0][mtc][rowc][u_l] + pl[3][0][mtc][rowc][u_l];
      float s1 = pl[0][1][mtc][rowc][u_l] + pl[1][1][mtc][rowc][u_l] +
                 pl[2][1][mtc][rowc][u_l] + pl[3][1][mtc][rowc][u_l];
      float s2 = pl[0][2][mtc][rowc][u_l] + pl[1][2][mtc][rowc][u_l] +
                 pl[2][2][mtc][rowc][u_l] + pl[3][2][mtc][rowc][u_l];
      float s3 = pl[0][3][mtc][rowc][u_l] + pl[1][3][mtc][rowc][u_l] +
                 pl[2][3][mtc][rowc][u_l] + pl[3][3][mtc][rowc][u_l];
      float gi = sigf(s0 + b0);
      float gf = sigf(s1 + b1);
      float gg = tanhfast(s2 + b2);
      float go = sigf(s3 + b3);
      float cv = gf * creg + gi * gg;
      creg = cv;
      float hv = go * tanhfast(cv);
      stg_h_sc(((p & 1) ? hA : hB) + hidx, (_Float16)hv);
      if (doY) {
        int ty = s - 2;
        float yv = pY[0][mtc][rowc][u_l] + pY[1][mtc][rowc][u_l] +
                   pY[2][mtc][rowc][u_l] + pY[3][mtc][rowc][u_l] + obv_cu;
        size_t ix = (size_t)cm * ((size_t)SS * DD) + (size_t)ty * DD + cu;
        recon[ix] = yv;
        float e = yv - x[ix];
        lossReg += e * e;   // register accumulation — no per-step atomics
      }
    }
    block_arrive(myslot, (unsigned)(p + 1));
  }

  // ---- final y (recon[:,511]) from final h (p=1023 wrote hA) ----
  bar_wait_all(bar, 1024u);
  if ((int)blockIdx.x < 64 && tid < 64) {
    const int fmt = (int)blockIdx.x >> 3, fdt = (int)blockIdx.x & 7;
    const int fm0 = fmt << 4, d0 = fdt << 4;
    floatx4 a4 = zero4;
    const _Float16* hrow = hA + (size_t)(fm0 + n) * HH + q * 8;
    const _Float16* orow = outW + (size_t)(d0 + n) * HH + q * 8;
    for (int kb = 0; kb < 32; kb += 8) {
      half8 hh[8];
#pragma unroll
      for (int j = 0; j < 8; ++j) hh[j] = ldg_h8_sc(hrow + (size_t)(kb + j) * 32);
      asm volatile("s_waitcnt vmcnt(0)" ::: "memory");
      __builtin_amdgcn_sched_barrier(0);
#pragma unroll
      for (int j = 0; j < 8; ++j)
        a4 = MFMA16(hh[j], *(const half8*)(orow + (size_t)(kb + j) * 32), a4);
    }
    int d = d0 + n;
    float ob2 = oB[d];
#pragma unroll
    for (int r = 0; r < 4; ++r) {
      int m = fm0 + q * 4 + r;
      float yv = a4[r] + ob2;
      size_t ix = (size_t)m * ((size_t)SS * DD) + (size_t)(SS - 1) * DD + d;
      recon[ix] = yv;
      float e = yv - x[ix];
      lossReg += e * e;
    }
  }

  // ---- block-wide loss reduction: ONE atomicAdd per block ----
#pragma unroll
  for (int off = 32; off; off >>= 1) lossReg += __shfl_xor(lossReg, off, 64);
  if (lane == 0) lred[w] = lossReg;
  __syncthreads();
  if (tid == 0) {
    float t = 0.0f;
#pragma unroll
    for (int i = 0; i < 8; ++i) t += lred[i];
    if (t != 0.0f) atomicAdd(lossAcc, t);
  }
  block_arrive(myslot, 1025u);
  bar_wait_all(bar, 1025u);
  if (blockIdx.x == 0 && tid == 0)
    lossOut[0] = __hip_atomic_load(lossAcc, __ATOMIC_RELAXED, __HIP_MEMORY_SCOPE_AGENT) *
                 (1.0f / (float)BB);
}

// ---- host -------------------------------------------------------------------

extern "C" void kernel_launch(void* const* d_in, const int* in_sizes, int n_in,
                              void* d_out, int out_size, void* d_ws, size_t ws_size,
                              hipStream_t stream) {
  const float* x    = (const float*)d_in[0];
  const float* eWih = (const float*)d_in[1];
  const float* eWhh = (const float*)d_in[2];
  const float* eBih = (const float*)d_in[3];
  const float* eBhh = (const float*)d_in[4];
  const float* dWih = (const float*)d_in[5];
  const float* dWhh = (const float*)d_in[6];
  const float* dBih = (const float*)d_in[7];
  const float* dBhh = (const float*)d_in[8];
  const float* oW   = (const float*)d_in[9];
  const float* oB   = (const float*)d_in[10];

  float* out = (float*)d_out;
  float* recon = out;                                   // (B,S,D)
  float* encOut = out + (size_t)BB * SS * DD;           // (B,S,H)
  float* lossOut = out + (size_t)BB * SS * DD + (size_t)BB * SS * HH;  // scalar

  char* p = (char*)d_ws;
  auto alloc = [&](size_t bytes) {
    char* r = p;
    p += (bytes + 255) & ~(size_t)255;
    return r;
  };
  _Float16* encW   = (_Float16*)alloc((size_t)G4 * KENC * 2);  // [Wih|Whh] fp16
  _Float16* decW1  = (_Float16*)alloc((size_t)G4 * HH * 2);
  _Float16* decW2  = (_Float16*)alloc((size_t)G4 * HH * 2);
  _Float16* outW16 = (_Float16*)alloc((size_t)DD * HH * 2);
  _Float16* x16    = (_Float16*)alloc((size_t)BB * SS * DD * 2);
  float* encB  = (float*)alloc((size_t)G4 * 4);
  float* decB1 = (float*)alloc((size_t)G4 * 4);
  float* decB2 = (float*)alloc((size_t)G4 * 4);
  _Float16* hA = (_Float16*)alloc((size_t)BB * HH * 2);
  _Float16* hB = (_Float16*)alloc((size_t)BB * HH * 2);
  float* lossAcc = (float*)alloc(256);
  unsigned* bar = (unsigned*)alloc((size_t)NBLK * SLOTSTRIDE * 4);
  (void)in_sizes; (void)n_in; (void)out_size; (void)ws_size;

  k_prep_encw<<<G4, 256, 0, stream>>>(eWih, eWhh, encW);
  k_prep_simple<<<2048, 256, 0, stream>>>(x, dWih, dWhh, oW, eBih, eBhh, dBih, dBhh, oB,
                                          x16, decW1, outW16, encB, decB1, decB2, hA,
                                          lossAcc, bar);
  k_prep_decw2<<<G4 * 4, 256, 0, stream>>>(dWih, dWhh, oW, decW2);

  void* args[] = {(void*)&x, (void*)&x16, (void*)&encW, (void*)&encB, (void*)&decW1,
                  (void*)&decW2, (void*)&decB1, (void*)&decB2, (void*)&outW16, (void*)&oB,
                  (void*)&hA, (void*)&hB, (void*)&encOut, (void*)&recon,
                  (void*)&lossAcc, (void*)&lossOut, (void*)&bar};
  (void)hipLaunchCooperativeKernel((void*)k_seq, dim3(NBLK), dim3(512), args, 0, stream);
}